// Round 1
// baseline (4224.304 us; speedup 1.0000x reference)
//
#include <hip/hip_runtime.h>

// TaxoRec forward pipeline on MI355X.
// Layout: per-node feature rows padded to 128 f32 (512 B): cols 0..62 enc1,
// 63..125 enc2, 126..127 zero pad. Both encoders share the graph -> fused.

__device__ __forceinline__ float wsum(float v) {
#pragma unroll
  for (int m = 32; m; m >>= 1) v += __shfl_xor(v, m, 64);
  return v;
}

// scale for logmap0 of projx(row): acosh(max(sqrt(1+ss),1+1e-7)) / sqrt(max(ss,1e-15))
__device__ __forceinline__ float logmap_scale(float ss) {
  float x0 = sqrtf(1.0f + ss);
  float alpha = fmaxf(x0, 1.0f + 1e-7f);
  float rnorm = sqrtf(fmaxf(ss, 1e-15f));
  return acoshf(alpha) / rnorm;
}

// xt[n,0:63) = logmap0(projx(emb[n])); rows < NU also get cols 63..125 from ugr.
__global__ __launch_bounds__(256) void k_node_prep(
    const float* __restrict__ emb, const float* __restrict__ ugr,
    float* __restrict__ xt, int N, int NU) {
  int n = blockIdx.x * 4 + (threadIdx.x >> 6);
  if (n >= N) return;
  int lane = threadIdx.x & 63;
  size_t base = (size_t)n * 128;
  float r1 = (lane < 63) ? emb[(size_t)n * 64 + 1 + lane] : 0.0f;
  float sc1 = logmap_scale(wsum(r1 * r1));
  if (lane < 63) xt[base + lane] = sc1 * r1;
  if (lane == 63) { xt[base + 126] = 0.0f; xt[base + 127] = 0.0f; }
  if (n < NU) {
    float r2 = (lane < 63) ? ugr[(size_t)n * 64 + 1 + lane] : 0.0f;
    float sc2 = logmap_scale(wsum(r2 * r2));
    if (lane < 63) xt[base + 63 + lane] = sc2 * r2;
  }
}

// per tag: gkg[t, 0:63) = gamma * k, gkg[t, 63] = gamma
__global__ __launch_bounds__(256) void k_tag_prep(
    const float* __restrict__ Tw, float* __restrict__ gkg, int TAGS) {
  int t = blockIdx.x * 4 + (threadIdx.x >> 6);
  if (t >= TAGS) return;
  int lane = threadIdx.x & 63;
  float r = (lane < 63) ? Tw[(size_t)t * 64 + 1 + lane] : 0.0f;
  float ss = wsum(r * r);
  float x0 = sqrtf(1.0f + ss);
  float p = r / (x0 + 1.0f);          // l2p (sk = 1)
  float sp = wsum(p * p);
  float k = 2.0f * p / (1.0f + sp);   // p2k
  float sk2 = wsum(k * k);
  float gamma = 1.0f / sqrtf(fmaxf(1.0f - sk2, 1e-15f));
  gkg[(size_t)t * 64 + lane] = (lane < 63) ? gamma * k : gamma;
}

// hyper_agg: one thread per item. num/den via 64-accumulator loop over 1024 tags,
// then k2p -> p2l -> logmap0 fused; writes xt[(NU+i), 63..125].
__global__ __launch_bounds__(256) void k_hyper(
    const float* __restrict__ sps, const float* __restrict__ gkg,
    float* __restrict__ xt, int NI, int NU) {
  int i = blockIdx.x * blockDim.x + threadIdx.x;
  if (i >= NI) return;
  float acc[64];
#pragma unroll
  for (int d = 0; d < 64; ++d) acc[d] = 0.0f;
  const float4* sr = (const float4*)(sps + (size_t)i * 1024);
  const float4* g4 = (const float4*)gkg;
  for (int t4 = 0; t4 < 256; ++t4) {
    float4 s4 = sr[t4];
    float sv[4] = {s4.x, s4.y, s4.z, s4.w};
#pragma unroll
    for (int j = 0; j < 4; ++j) {
      float s = sv[j];
      const float4* g = g4 + (size_t)(t4 * 4 + j) * 16;
#pragma unroll
      for (int d4 = 0; d4 < 16; ++d4) {
        float4 gv = g[d4];
        acc[d4 * 4 + 0] = fmaf(s, gv.x, acc[d4 * 4 + 0]);
        acc[d4 * 4 + 1] = fmaf(s, gv.y, acc[d4 * 4 + 1]);
        acc[d4 * 4 + 2] = fmaf(s, gv.z, acc[d4 * 4 + 2]);
        acc[d4 * 4 + 3] = fmaf(s, gv.w, acc[d4 * 4 + 3]);
      }
    }
  }
  float den = fmaxf(acc[63], 1e-15f);
  float sy = 0.0f;
#pragma unroll
  for (int d = 0; d < 63; ++d) { float y = acc[d] / den; acc[d] = y; sy += y * y; }
  float dk = 1.0f + sqrtf(fmaxf(1.0f - sy, 1e-15f));   // k2p denom
  float nq = 0.0f;
#pragma unroll
  for (int d = 0; d < 63; ++d) { float q = acc[d] / dk; acc[d] = q; nq += q * q; }
  float f = 1.0f / (1.0f - nq + 1e-6f);                // p2l
  float row0 = (1.0f + nq) * f;
  float srr = 0.0f;
#pragma unroll
  for (int d = 0; d < 63; ++d) { float r = 2.0f * acc[d] * f; acc[d] = r; srr += r * r; }
  float alpha = fmaxf(row0, 1.0f + 1e-7f);             // logmap0
  float scale = acoshf(alpha) / sqrtf(fmaxf(srr, 1e-15f));
  float* dst = xt + (size_t)(NU + i) * 128 + 63;
#pragma unroll
  for (int d = 0; d < 63; ++d) dst[d] = scale * acc[d];
}

// one layer of fused segment-sum: nxt[dst] += w * cur[src] over 126 dims.
__global__ __launch_bounds__(256) void k_edge(
    const float* __restrict__ cur, float* __restrict__ nxt,
    const int* __restrict__ esrc, const int* __restrict__ edst,
    const float* __restrict__ ew, int E) {
  int e = blockIdx.x * 4 + (threadIdx.x >> 6);
  if (e >= E) return;
  int lane = threadIdx.x & 63;
  int s = esrc[e], d = edst[e];
  float w = ew[e];
  float2 v = ((const float2*)(cur + (size_t)s * 128))[lane];
  if (lane < 63) {
    float* drow = nxt + (size_t)d * 128 + 2 * lane;
    atomicAdd(drow, w * v.x);
    atomicAdd(drow + 1, w * v.y);
  }
}

// h[n] = [expmap0(acc_enc1) | expmap0(acc_enc2)], acc = l1 + l2 + l3 outputs.
__global__ __launch_bounds__(256) void k_expmap(
    const float* __restrict__ n1, const float* __restrict__ n2,
    const float* __restrict__ n3, float* __restrict__ h, int N) {
  int n = blockIdx.x * 4 + (threadIdx.x >> 6);
  if (n >= N) return;
  int lane = threadIdx.x & 63;
  size_t b = (size_t)n * 128;
  float a0 = 0.0f, a1 = 0.0f;
  if (lane < 63) {
    a0 = n1[b + lane] + n2[b + lane] + n3[b + lane];
    a1 = n1[b + 63 + lane] + n2[b + 63 + lane] + n3[b + 63 + lane];
  }
  float ss0 = wsum(a0 * a0), ss1 = wsum(a1 * a1);
  float nn0 = sqrtf(fmaxf(ss0, 1e-15f)), nn1 = sqrtf(fmaxf(ss1, 1e-15f));
  float s0 = sinhf(nn0) / nn0, s1 = sinhf(nn1) / nn1;
  if (lane < 63) {
    h[b + 1 + lane] = s0 * a0;
    h[b + 65 + lane] = s1 * a1;
  } else {
    h[b] = coshf(nn0);
    h[b + 64] = coshf(nn1);
  }
}

// out[b] = min(dist2(h[u,0:64],h[v,0:64]),50) + min(dist2(h[u,64:128],h[v,64:128]),15)
__global__ __launch_bounds__(256) void k_score(
    const float* __restrict__ h, const int* __restrict__ idx,
    float* __restrict__ out, int B) {
  int b = blockIdx.x * 4 + (threadIdx.x >> 6);
  if (b >= B) return;
  int lane = threadIdx.x & 63;
  int u = idx[2 * b], v = idx[2 * b + 1];
  float2 hu = ((const float2*)(h + (size_t)u * 128))[lane];
  float2 hv = ((const float2*)(h + (size_t)v * 128))[lane];
  float px = hu.x * hv.x;
  if (lane == 0 || lane == 32) px = -px;   // time components at cols 0 and 64
  float p = px + hu.y * hv.y;
#pragma unroll
  for (int m = 1; m < 32; m <<= 1) p += __shfl_xor(p, m, 64);  // per-32-half sums
  float dd = fmaxf(-p, 1.0f + 1e-7f);
  float a = acoshf(dd);
  float s = fminf(a * a, (lane < 32) ? 50.0f : 15.0f);
  s += __shfl_xor(s, 32, 64);
  if (lane == 0) out[b] = s;
}

extern "C" void kernel_launch(void* const* d_in, const int* in_sizes, int n_in,
                              void* d_out, int out_size, void* d_ws, size_t ws_size,
                              hipStream_t stream) {
  const float* emb = (const float*)d_in[0];
  const float* Tw  = (const float*)d_in[1];
  const float* ugr = (const float*)d_in[2];
  const float* sps = (const float*)d_in[3];
  const float* ew  = (const float*)d_in[4];
  const int* esrc  = (const int*)d_in[5];
  const int* edst  = (const int*)d_in[6];
  const int* idx   = (const int*)d_in[7];
  float* out = (float*)d_out;

  const int N    = in_sizes[0] / 64;   // 49152
  const int TAGS = in_sizes[1] / 64;   // 1024
  const int NU   = in_sizes[2] / 64;   // 8192
  const int NI   = in_sizes[3] / TAGS; // 40960
  const int E    = in_sizes[4];        // 1572864
  const int B    = in_sizes[7] / 2;    // 131072

  size_t rowsz = (size_t)N * 128 * sizeof(float);
  char* ws = (char*)d_ws;
  float* xt  = (float*)(ws);               // layer0 input; reused as layer-3 output
  float* b1  = (float*)(ws + rowsz);       // layer1 output
  float* b2  = (float*)(ws + 2 * rowsz);   // layer2 output
  float* h   = (float*)(ws + 3 * rowsz);   // final embeddings (N x 128)
  float* gkg = (float*)(ws + 4 * rowsz);   // TAGS x 64: gamma*k | gamma

  hipMemsetAsync(b1, 0, rowsz, stream);
  hipMemsetAsync(b2, 0, rowsz, stream);

  k_node_prep<<<(N + 3) / 4, 256, 0, stream>>>(emb, ugr, xt, N, NU);
  k_tag_prep<<<(TAGS + 3) / 4, 256, 0, stream>>>(Tw, gkg, TAGS);
  k_hyper<<<(NI + 255) / 256, 256, 0, stream>>>(sps, gkg, xt, NI, NU);

  k_edge<<<(E + 3) / 4, 256, 0, stream>>>(xt, b1, esrc, edst, ew, E);
  k_edge<<<(E + 3) / 4, 256, 0, stream>>>(b1, b2, esrc, edst, ew, E);
  hipMemsetAsync(xt, 0, rowsz, stream);       // reuse xt as layer-3 accumulator
  k_edge<<<(E + 3) / 4, 256, 0, stream>>>(b2, xt, esrc, edst, ew, E);

  k_expmap<<<(N + 3) / 4, 256, 0, stream>>>(b1, b2, xt, h, N);
  k_score<<<(B + 3) / 4, 256, 0, stream>>>(h, idx, out, B);
}

// Round 2
// 964.683 us; speedup vs baseline: 4.3790x; 4.3790x over previous
//
#include <hip/hip_runtime.h>

// TaxoRec forward pipeline on MI355X — round 2.
// Node feature rows padded to 128 f32 (512 B): cols 0..62 enc1, 63..125 enc2,
// 126..127 zero pad. Both encoders share the graph (fused feature rows).
// Edge segment-sum is done via CSR (group by dst) + gather-side register
// reduction: no float atomics, each output row written exactly once.

__device__ __forceinline__ float wsum(float v) {
#pragma unroll
  for (int m = 32; m; m >>= 1) v += __shfl_xor(v, m, 64);
  return v;
}

__device__ __forceinline__ float logmap_scale(float ss) {
  float x0 = sqrtf(1.0f + ss);
  float alpha = fmaxf(x0, 1.0f + 1e-7f);
  float rnorm = sqrtf(fmaxf(ss, 1e-15f));
  return acoshf(alpha) / rnorm;
}

// xt[n,0:63) = logmap0(projx(emb[n])); rows < NU also get cols 63..125 from ugr.
__global__ __launch_bounds__(256) void k_node_prep(
    const float* __restrict__ emb, const float* __restrict__ ugr,
    float* __restrict__ xt, int N, int NU) {
  int n = blockIdx.x * 4 + (threadIdx.x >> 6);
  if (n >= N) return;
  int lane = threadIdx.x & 63;
  size_t base = (size_t)n * 128;
  float r1 = (lane < 63) ? emb[(size_t)n * 64 + 1 + lane] : 0.0f;
  float sc1 = logmap_scale(wsum(r1 * r1));
  if (lane < 63) xt[base + lane] = sc1 * r1;
  if (lane == 63) { xt[base + 126] = 0.0f; xt[base + 127] = 0.0f; }
  if (n < NU) {
    float r2 = (lane < 63) ? ugr[(size_t)n * 64 + 1 + lane] : 0.0f;
    float sc2 = logmap_scale(wsum(r2 * r2));
    if (lane < 63) xt[base + 63 + lane] = sc2 * r2;
  }
}

// per tag: gkg[t, 0:63) = gamma * k, gkg[t, 63] = gamma
__global__ __launch_bounds__(256) void k_tag_prep(
    const float* __restrict__ Tw, float* __restrict__ gkg, int TAGS) {
  int t = blockIdx.x * 4 + (threadIdx.x >> 6);
  if (t >= TAGS) return;
  int lane = threadIdx.x & 63;
  float r = (lane < 63) ? Tw[(size_t)t * 64 + 1 + lane] : 0.0f;
  float ss = wsum(r * r);
  float x0 = sqrtf(1.0f + ss);
  float p = r / (x0 + 1.0f);          // l2p (sk = 1)
  float sp = wsum(p * p);
  float k = 2.0f * p / (1.0f + sp);   // p2k
  float sk2 = wsum(k * k);
  float gamma = 1.0f / sqrtf(fmaxf(1.0f - sk2, 1e-15f));
  gkg[(size_t)t * 64 + lane] = (lane < 63) ? gamma * k : gamma;
}

// hyper_agg: one thread per item; 64 accumulators over 1024 tags, then
// k2p -> p2l -> logmap0 fused; writes xt[(NU+i), 63..125].
__global__ __launch_bounds__(256) void k_hyper(
    const float* __restrict__ sps, const float* __restrict__ gkg,
    float* __restrict__ xt, int NI, int NU) {
  int i = blockIdx.x * blockDim.x + threadIdx.x;
  if (i >= NI) return;
  float acc[64];
#pragma unroll
  for (int d = 0; d < 64; ++d) acc[d] = 0.0f;
  const float4* sr = (const float4*)(sps + (size_t)i * 1024);
  const float4* g4 = (const float4*)gkg;
  for (int t4 = 0; t4 < 256; ++t4) {
    float4 s4 = sr[t4];
    float sv[4] = {s4.x, s4.y, s4.z, s4.w};
#pragma unroll
    for (int j = 0; j < 4; ++j) {
      float s = sv[j];
      const float4* g = g4 + (size_t)(t4 * 4 + j) * 16;
#pragma unroll
      for (int d4 = 0; d4 < 16; ++d4) {
        float4 gv = g[d4];
        acc[d4 * 4 + 0] = fmaf(s, gv.x, acc[d4 * 4 + 0]);
        acc[d4 * 4 + 1] = fmaf(s, gv.y, acc[d4 * 4 + 1]);
        acc[d4 * 4 + 2] = fmaf(s, gv.z, acc[d4 * 4 + 2]);
        acc[d4 * 4 + 3] = fmaf(s, gv.w, acc[d4 * 4 + 3]);
      }
    }
  }
  float den = fmaxf(acc[63], 1e-15f);
  float sy = 0.0f;
#pragma unroll
  for (int d = 0; d < 63; ++d) { float y = acc[d] / den; acc[d] = y; sy += y * y; }
  float dk = 1.0f + sqrtf(fmaxf(1.0f - sy, 1e-15f));   // k2p denom
  float nq = 0.0f;
#pragma unroll
  for (int d = 0; d < 63; ++d) { float q = acc[d] / dk; acc[d] = q; nq += q * q; }
  float f = 1.0f / (1.0f - nq + 1e-6f);                // p2l
  float row0 = (1.0f + nq) * f;
  float srr = 0.0f;
#pragma unroll
  for (int d = 0; d < 63; ++d) { float r = 2.0f * acc[d] * f; acc[d] = r; srr += r * r; }
  float alpha = fmaxf(row0, 1.0f + 1e-7f);             // logmap0
  float scale = acoshf(alpha) / sqrtf(fmaxf(srr, 1e-15f));
  float* dst = xt + (size_t)(NU + i) * 128 + 63;
#pragma unroll
  for (int d = 0; d < 63; ++d) dst[d] = scale * acc[d];
}

// ---- CSR build ----------------------------------------------------------

// histogram of edge destinations into pos[] (pre-zeroed)
__global__ __launch_bounds__(256) void k_hist(
    const int* __restrict__ edst, int* __restrict__ pos, int E) {
  int e = blockIdx.x * blockDim.x + threadIdx.x;
  if (e < E) atomicAdd(&pos[edst[e]], 1);
}

// single-block exclusive scan: pos[] holds degrees in, scatter cursors out;
// off[] gets the exclusive prefix (off[N] = E).
__global__ __launch_bounds__(1024) void k_scan(
    int* pos, int* __restrict__ off, int N) {
  __shared__ int part[1024];
  int t = threadIdx.x;
  int chunk = (N + 1023) >> 10;
  int beg = t * chunk, end = min(beg + chunk, N);
  int s = 0;
  for (int i = beg; i < end; ++i) s += pos[i];
  part[t] = s;
  __syncthreads();
  for (int d = 1; d < 1024; d <<= 1) {
    int v = (t >= d) ? part[t - d] : 0;
    __syncthreads();
    part[t] += v;
    __syncthreads();
  }
  int run = (t == 0) ? 0 : part[t - 1];
  for (int i = beg; i < end; ++i) {
    int dg = pos[i];
    off[i] = run;
    pos[i] = run;
    run += dg;
  }
  if (t == 1023) off[N] = run;
}

// scatter edges into CSR slots: rec[p] = (src, w), p = cursor++ for dst
__global__ __launch_bounds__(256) void k_scatter(
    const int* __restrict__ esrc, const int* __restrict__ edst,
    const float* __restrict__ ew, int* __restrict__ pos,
    int2* __restrict__ rec, int E) {
  int e = blockIdx.x * blockDim.x + threadIdx.x;
  if (e >= E) return;
  int p = atomicAdd(&pos[edst[e]], 1);
  rec[p] = make_int2(esrc[e], __float_as_int(ew[e]));
}

// ---- one encoder layer: gather-side segment-sum -------------------------
// wave per dst node: acc(2 f32/lane) += w * cur[src] over incident edges.
__global__ __launch_bounds__(256) void k_gather(
    const float* __restrict__ cur, float* __restrict__ nxt,
    const int* __restrict__ off, const int2* __restrict__ rec, int N) {
  int n = blockIdx.x * 4 + (threadIdx.x >> 6);
  if (n >= N) return;
  int lane = threadIdx.x & 63;
  int beg = off[n], end = off[n + 1];
  float ax = 0.0f, ay = 0.0f;
  for (int j = beg; j < end; j += 64) {
    int cnt = min(64, end - j);
    int sv = 0; float wv = 0.0f;
    if (lane < cnt) {
      int2 r = rec[j + lane];
      sv = r.x;
      wv = __int_as_float(r.y);
    }
    int k = 0;
    for (; k + 1 < cnt; k += 2) {
      int s0 = __shfl(sv, k, 64), s1 = __shfl(sv, k + 1, 64);
      float w0 = __shfl(wv, k, 64), w1 = __shfl(wv, k + 1, 64);
      float2 v0 = ((const float2*)(cur + (size_t)s0 * 128))[lane];
      float2 v1 = ((const float2*)(cur + (size_t)s1 * 128))[lane];
      ax = fmaf(w0, v0.x, ax); ay = fmaf(w0, v0.y, ay);
      ax = fmaf(w1, v1.x, ax); ay = fmaf(w1, v1.y, ay);
    }
    if (k < cnt) {
      int s0 = __shfl(sv, k, 64);
      float w0 = __shfl(wv, k, 64);
      float2 v0 = ((const float2*)(cur + (size_t)s0 * 128))[lane];
      ax = fmaf(w0, v0.x, ax); ay = fmaf(w0, v0.y, ay);
    }
  }
  ((float2*)(nxt + (size_t)n * 128))[lane] = make_float2(ax, ay);
}

// h[n] = [expmap0(acc_enc1) | expmap0(acc_enc2)]; h may alias n1 (in-place):
// all reads complete in-wave before any write. No __restrict__ here.
__global__ __launch_bounds__(256) void k_expmap(
    const float* n1, const float* n2, const float* n3, float* h, int N) {
  int n = blockIdx.x * 4 + (threadIdx.x >> 6);
  if (n >= N) return;
  int lane = threadIdx.x & 63;
  size_t b = (size_t)n * 128;
  float a0 = 0.0f, a1 = 0.0f;
  if (lane < 63) {
    a0 = n1[b + lane] + n2[b + lane] + n3[b + lane];
    a1 = n1[b + 63 + lane] + n2[b + 63 + lane] + n3[b + 63 + lane];
  }
  float ss0 = wsum(a0 * a0), ss1 = wsum(a1 * a1);
  float nn0 = sqrtf(fmaxf(ss0, 1e-15f)), nn1 = sqrtf(fmaxf(ss1, 1e-15f));
  float s0 = sinhf(nn0) / nn0, s1 = sinhf(nn1) / nn1;
  if (lane < 63) {
    h[b + 1 + lane] = s0 * a0;
    h[b + 65 + lane] = s1 * a1;
  } else {
    h[b] = coshf(nn0);
    h[b + 64] = coshf(nn1);
  }
}

// out[b] = min(dist2(h[u,:64],h[v,:64]),50) + min(dist2(h[u,64:],h[v,64:]),15)
__global__ __launch_bounds__(256) void k_score(
    const float* __restrict__ h, const int* __restrict__ idx,
    float* __restrict__ out, int B) {
  int b = blockIdx.x * 4 + (threadIdx.x >> 6);
  if (b >= B) return;
  int lane = threadIdx.x & 63;
  int u = idx[2 * b], v = idx[2 * b + 1];
  float2 hu = ((const float2*)(h + (size_t)u * 128))[lane];
  float2 hv = ((const float2*)(h + (size_t)v * 128))[lane];
  float px = hu.x * hv.x;
  if (lane == 0 || lane == 32) px = -px;   // time components at cols 0 and 64
  float p = px + hu.y * hv.y;
#pragma unroll
  for (int m = 1; m < 32; m <<= 1) p += __shfl_xor(p, m, 64);  // per-half sums
  float dd = fmaxf(-p, 1.0f + 1e-7f);
  float a = acoshf(dd);
  float s = fminf(a * a, (lane < 32) ? 50.0f : 15.0f);
  s += __shfl_xor(s, 32, 64);
  if (lane == 0) out[b] = s;
}

extern "C" void kernel_launch(void* const* d_in, const int* in_sizes, int n_in,
                              void* d_out, int out_size, void* d_ws, size_t ws_size,
                              hipStream_t stream) {
  const float* emb = (const float*)d_in[0];
  const float* Tw  = (const float*)d_in[1];
  const float* ugr = (const float*)d_in[2];
  const float* sps = (const float*)d_in[3];
  const float* ew  = (const float*)d_in[4];
  const int* esrc  = (const int*)d_in[5];
  const int* edst  = (const int*)d_in[6];
  const int* idx   = (const int*)d_in[7];
  float* out = (float*)d_out;

  const int N    = in_sizes[0] / 64;   // 49152
  const int TAGS = in_sizes[1] / 64;   // 1024
  const int NU   = in_sizes[2] / 64;   // 8192
  const int NI   = in_sizes[3] / TAGS; // 40960
  const int E    = in_sizes[4];        // 1572864
  const int B    = in_sizes[7] / 2;    // 131072

  size_t rowsz = (size_t)N * 128 * sizeof(float);
  char* ws = (char*)d_ws;
  float* xt  = (float*)(ws);               // layer0 input; reused as layer-3 out
  float* b1  = (float*)(ws + rowsz);       // layer1 out; later aliased by h
  float* b2  = (float*)(ws + 2 * rowsz);   // layer2 out
  float* gkg = (float*)(ws + 3 * rowsz);   // TAGS x 64
  size_t o = 3 * rowsz + (size_t)TAGS * 64 * sizeof(float);
  int* off = (int*)(ws + o);  o += (size_t)(N + 1) * sizeof(int);
  int* pos = (int*)(ws + o);  o += (size_t)N * sizeof(int);
  o = (o + 7) & ~(size_t)7;
  int2* rec = (int2*)(ws + o);             // E records (src, w)
  float* h = b1;                           // expmap output, in-place over b1

  // CSR build
  hipMemsetAsync(pos, 0, (size_t)N * sizeof(int), stream);
  k_hist<<<(E + 255) / 256, 256, 0, stream>>>(edst, pos, E);
  k_scan<<<1, 1024, 0, stream>>>(pos, off, N);
  k_scatter<<<(E + 255) / 256, 256, 0, stream>>>(esrc, edst, ew, pos, rec, E);

  // feature prep
  k_node_prep<<<(N + 3) / 4, 256, 0, stream>>>(emb, ugr, xt, N, NU);
  k_tag_prep<<<(TAGS + 3) / 4, 256, 0, stream>>>(Tw, gkg, TAGS);
  k_hyper<<<(NI + 255) / 256, 256, 0, stream>>>(sps, gkg, xt, NI, NU);

  // 3 encoder layers (gather-side, no atomics)
  k_gather<<<(N + 3) / 4, 256, 0, stream>>>(xt, b1, off, rec, N);
  k_gather<<<(N + 3) / 4, 256, 0, stream>>>(b1, b2, off, rec, N);
  k_gather<<<(N + 3) / 4, 256, 0, stream>>>(b2, xt, off, rec, N);

  k_expmap<<<(N + 3) / 4, 256, 0, stream>>>(b1, b2, xt, h, N);
  k_score<<<(B + 3) / 4, 256, 0, stream>>>(h, idx, out, B);
}

// Round 3
// 798.068 us; speedup vs baseline: 5.2932x; 1.2088x over previous
//
#include <hip/hip_runtime.h>

// TaxoRec forward pipeline on MI355X — round 3.
// Node feature rows padded to 128 f32 (512 B): cols 0..62 enc1, 63..125 enc2.
// Edge segment-sum via CSR + gather-side register reduction (no f32 atomics).
// hyper_agg is now a tiled LDS GEMM (64 items x 64 dims per block, K=1024).

__device__ __forceinline__ float wsum(float v) {
#pragma unroll
  for (int m = 32; m; m >>= 1) v += __shfl_xor(v, m, 64);
  return v;
}

__device__ __forceinline__ float logmap_scale(float ss) {
  float x0 = sqrtf(1.0f + ss);
  float alpha = fmaxf(x0, 1.0f + 1e-7f);
  float rnorm = sqrtf(fmaxf(ss, 1e-15f));
  return acoshf(alpha) / rnorm;
}

// xt[n,0:63) = logmap0(projx(emb[n])); rows < NU also get cols 63..125 from ugr.
__global__ __launch_bounds__(256) void k_node_prep(
    const float* __restrict__ emb, const float* __restrict__ ugr,
    float* __restrict__ xt, int N, int NU) {
  int n = blockIdx.x * 4 + (threadIdx.x >> 6);
  if (n >= N) return;
  int lane = threadIdx.x & 63;
  size_t base = (size_t)n * 128;
  float r1 = (lane < 63) ? emb[(size_t)n * 64 + 1 + lane] : 0.0f;
  float sc1 = logmap_scale(wsum(r1 * r1));
  if (lane < 63) xt[base + lane] = sc1 * r1;
  if (lane == 63) { xt[base + 126] = 0.0f; xt[base + 127] = 0.0f; }
  if (n < NU) {
    float r2 = (lane < 63) ? ugr[(size_t)n * 64 + 1 + lane] : 0.0f;
    float sc2 = logmap_scale(wsum(r2 * r2));
    if (lane < 63) xt[base + 63 + lane] = sc2 * r2;
  }
}

// per tag: gkg[t, 0:63) = gamma * k, gkg[t, 63] = gamma
__global__ __launch_bounds__(256) void k_tag_prep(
    const float* __restrict__ Tw, float* __restrict__ gkg, int TAGS) {
  int t = blockIdx.x * 4 + (threadIdx.x >> 6);
  if (t >= TAGS) return;
  int lane = threadIdx.x & 63;
  float r = (lane < 63) ? Tw[(size_t)t * 64 + 1 + lane] : 0.0f;
  float ss = wsum(r * r);
  float x0 = sqrtf(1.0f + ss);
  float p = r / (x0 + 1.0f);          // l2p (sk = 1)
  float sp = wsum(p * p);
  float k = 2.0f * p / (1.0f + sp);   // p2k
  float sk2 = wsum(k * k);
  float gamma = 1.0f / sqrtf(fmaxf(1.0f - sk2, 1e-15f));
  gkg[(size_t)t * 64 + lane] = (lane < 63) ? gamma * k : gamma;
}

// hyper_agg as tiled GEMM: block = 64 items x 64 dims, K-loop 16 x 64 tags.
// Thread (tx=tid&15, ty=tid>>4) owns items ty*4..+4, dims tx*4..+4 (4x4 acc).
// Epilogue: acc tile -> LDS, wave per 16 items runs k2p->p2l->logmap0 chain.
__global__ __launch_bounds__(256) void k_hyper(
    const float* __restrict__ sps, const float* __restrict__ gkg,
    float* __restrict__ xt, int NI, int NU) {
  __shared__ float s_tile[64][68];   // [item][tag], padded
  __shared__ float g_tile[64][64];   // [tag][dim]
  int tid = threadIdx.x;
  int tx = tid & 15, ty = tid >> 4;
  int ib = blockIdx.x * 64;          // first item of this block
  float acc[4][4];
#pragma unroll
  for (int c = 0; c < 4; ++c)
#pragma unroll
    for (int d = 0; d < 4; ++d) acc[c][d] = 0.0f;

  const float4* sps4 = (const float4*)sps;
  const float4* gkg4 = (const float4*)gkg;

  for (int kc = 0; kc < 16; ++kc) {
    // stage: each thread loads 4 float4 of sps and 4 float4 of gkg
#pragma unroll
    for (int r = 0; r < 4; ++r) {
      int row = ty + 16 * r;  // item within tile / tag within chunk
      float4 sv = sps4[(size_t)(ib + row) * 256 + kc * 16 + tx];
      *(float4*)&s_tile[row][tx * 4] = sv;
      float4 gv = gkg4[(size_t)(kc * 64 + row) * 16 + tx];
      *(float4*)&g_tile[row][tx * 4] = gv;
    }
    __syncthreads();
    // compute: tag groups of 4
#pragma unroll
    for (int tg = 0; tg < 16; ++tg) {
      float4 s4[4], g4[4];
#pragma unroll
      for (int c = 0; c < 4; ++c) s4[c] = *(const float4*)&s_tile[ty * 4 + c][tg * 4];
#pragma unroll
      for (int j = 0; j < 4; ++j) g4[j] = *(const float4*)&g_tile[tg * 4 + j][tx * 4];
#pragma unroll
      for (int c = 0; c < 4; ++c) {
        float sv[4] = {s4[c].x, s4[c].y, s4[c].z, s4[c].w};
#pragma unroll
        for (int j = 0; j < 4; ++j) {
          acc[c][0] = fmaf(sv[j], g4[j].x, acc[c][0]);
          acc[c][1] = fmaf(sv[j], g4[j].y, acc[c][1]);
          acc[c][2] = fmaf(sv[j], g4[j].z, acc[c][2]);
          acc[c][3] = fmaf(sv[j], g4[j].w, acc[c][3]);
        }
      }
    }
    __syncthreads();
  }

  // dump accumulators to LDS (reuse s_tile): e[item][dim]
#pragma unroll
  for (int c = 0; c < 4; ++c)
    *(float4*)&s_tile[ty * 4 + c][tx * 4] = make_float4(acc[c][0], acc[c][1], acc[c][2], acc[c][3]);
  __syncthreads();

  // epilogue: wave w handles items w*16 .. w*16+15; lane = dim
  int w = tid >> 6, lane = tid & 63;
  for (int it = 0; it < 16; ++it) {
    int i = w * 16 + it;
    float v = s_tile[i][lane];
    float den = fmaxf(__shfl(v, 63, 64), 1e-15f);
    float y = v / den;
    float sy = wsum((lane < 63) ? y * y : 0.0f);
    float dk = 1.0f + sqrtf(fmaxf(1.0f - sy, 1e-15f));   // k2p denom
    float q = y / dk;
    float nq = wsum((lane < 63) ? q * q : 0.0f);
    float f = 1.0f / (1.0f - nq + 1e-6f);                // p2l
    float row0 = (1.0f + nq) * f;
    float r = 2.0f * q * f;
    float srr = wsum((lane < 63) ? r * r : 0.0f);
    float alpha = fmaxf(row0, 1.0f + 1e-7f);             // logmap0
    float scale = acoshf(alpha) / sqrtf(fmaxf(srr, 1e-15f));
    if (lane < 63)
      xt[(size_t)(NU + ib + i) * 128 + 63 + lane] = scale * r;
  }
}

// ---- CSR build ----------------------------------------------------------

__global__ __launch_bounds__(256) void k_hist(
    const int* __restrict__ edst, int* __restrict__ pos, int E) {
  int e = blockIdx.x * blockDim.x + threadIdx.x;
  if (e < E) atomicAdd(&pos[edst[e]], 1);
}

__global__ __launch_bounds__(1024) void k_scan(
    int* pos, int* __restrict__ off, int N) {
  __shared__ int part[1024];
  int t = threadIdx.x;
  int chunk = (N + 1023) >> 10;
  int beg = t * chunk, end = min(beg + chunk, N);
  int s = 0;
  for (int i = beg; i < end; ++i) s += pos[i];
  part[t] = s;
  __syncthreads();
  for (int d = 1; d < 1024; d <<= 1) {
    int v = (t >= d) ? part[t - d] : 0;
    __syncthreads();
    part[t] += v;
    __syncthreads();
  }
  int run = (t == 0) ? 0 : part[t - 1];
  for (int i = beg; i < end; ++i) {
    int dg = pos[i];
    off[i] = run;
    pos[i] = run;
    run += dg;
  }
  if (t == 1023) off[N] = run;
}

__global__ __launch_bounds__(256) void k_scatter(
    const int* __restrict__ esrc, const int* __restrict__ edst,
    const float* __restrict__ ew, int* __restrict__ pos,
    int2* __restrict__ rec, int E) {
  int e = blockIdx.x * blockDim.x + threadIdx.x;
  if (e >= E) return;
  int p = atomicAdd(&pos[edst[e]], 1);
  rec[p] = make_int2(esrc[e], __float_as_int(ew[e]));
}

// ---- one encoder layer: gather-side segment-sum -------------------------
__global__ __launch_bounds__(256) void k_gather(
    const float* __restrict__ cur, float* __restrict__ nxt,
    const int* __restrict__ off, const int2* __restrict__ rec, int N) {
  int n = blockIdx.x * 4 + (threadIdx.x >> 6);
  if (n >= N) return;
  int lane = threadIdx.x & 63;
  int beg = off[n], end = off[n + 1];
  float ax = 0.0f, ay = 0.0f;
  for (int j = beg; j < end; j += 64) {
    int cnt = min(64, end - j);
    int sv = 0; float wv = 0.0f;
    if (lane < cnt) {
      int2 r = rec[j + lane];
      sv = r.x;
      wv = __int_as_float(r.y);
    }
    int k = 0;
    for (; k + 1 < cnt; k += 2) {
      int s0 = __shfl(sv, k, 64), s1 = __shfl(sv, k + 1, 64);
      float w0 = __shfl(wv, k, 64), w1 = __shfl(wv, k + 1, 64);
      float2 v0 = ((const float2*)(cur + (size_t)s0 * 128))[lane];
      float2 v1 = ((const float2*)(cur + (size_t)s1 * 128))[lane];
      ax = fmaf(w0, v0.x, ax); ay = fmaf(w0, v0.y, ay);
      ax = fmaf(w1, v1.x, ax); ay = fmaf(w1, v1.y, ay);
    }
    if (k < cnt) {
      int s0 = __shfl(sv, k, 64);
      float w0 = __shfl(wv, k, 64);
      float2 v0 = ((const float2*)(cur + (size_t)s0 * 128))[lane];
      ax = fmaf(w0, v0.x, ax); ay = fmaf(w0, v0.y, ay);
    }
  }
  ((float2*)(nxt + (size_t)n * 128))[lane] = make_float2(ax, ay);
}

// h[n] = [expmap0(acc_enc1) | expmap0(acc_enc2)]; h aliases n1 (in-place).
__global__ __launch_bounds__(256) void k_expmap(
    const float* n1, const float* n2, const float* n3, float* h, int N) {
  int n = blockIdx.x * 4 + (threadIdx.x >> 6);
  if (n >= N) return;
  int lane = threadIdx.x & 63;
  size_t b = (size_t)n * 128;
  float a0 = 0.0f, a1 = 0.0f;
  if (lane < 63) {
    a0 = n1[b + lane] + n2[b + lane] + n3[b + lane];
    a1 = n1[b + 63 + lane] + n2[b + 63 + lane] + n3[b + 63 + lane];
  }
  float ss0 = wsum(a0 * a0), ss1 = wsum(a1 * a1);
  float nn0 = sqrtf(fmaxf(ss0, 1e-15f)), nn1 = sqrtf(fmaxf(ss1, 1e-15f));
  float s0 = sinhf(nn0) / nn0, s1 = sinhf(nn1) / nn1;
  if (lane < 63) {
    h[b + 1 + lane] = s0 * a0;
    h[b + 65 + lane] = s1 * a1;
  } else {
    h[b] = coshf(nn0);
    h[b + 64] = coshf(nn1);
  }
}

// out[b] = min(dist2(h[u,:64],h[v,:64]),50) + min(dist2(h[u,64:],h[v,64:]),15)
__global__ __launch_bounds__(256) void k_score(
    const float* __restrict__ h, const int* __restrict__ idx,
    float* __restrict__ out, int B) {
  int b = blockIdx.x * 4 + (threadIdx.x >> 6);
  if (b >= B) return;
  int lane = threadIdx.x & 63;
  int u = idx[2 * b], v = idx[2 * b + 1];
  float2 hu = ((const float2*)(h + (size_t)u * 128))[lane];
  float2 hv = ((const float2*)(h + (size_t)v * 128))[lane];
  float px = hu.x * hv.x;
  if (lane == 0 || lane == 32) px = -px;   // time components at cols 0 and 64
  float p = px + hu.y * hv.y;
#pragma unroll
  for (int m = 1; m < 32; m <<= 1) p += __shfl_xor(p, m, 64);  // per-half sums
  float dd = fmaxf(-p, 1.0f + 1e-7f);
  float a = acoshf(dd);
  float s = fminf(a * a, (lane < 32) ? 50.0f : 15.0f);
  s += __shfl_xor(s, 32, 64);
  if (lane == 0) out[b] = s;
}

extern "C" void kernel_launch(void* const* d_in, const int* in_sizes, int n_in,
                              void* d_out, int out_size, void* d_ws, size_t ws_size,
                              hipStream_t stream) {
  const float* emb = (const float*)d_in[0];
  const float* Tw  = (const float*)d_in[1];
  const float* ugr = (const float*)d_in[2];
  const float* sps = (const float*)d_in[3];
  const float* ew  = (const float*)d_in[4];
  const int* esrc  = (const int*)d_in[5];
  const int* edst  = (const int*)d_in[6];
  const int* idx   = (const int*)d_in[7];
  float* out = (float*)d_out;

  const int N    = in_sizes[0] / 64;   // 49152
  const int TAGS = in_sizes[1] / 64;   // 1024
  const int NU   = in_sizes[2] / 64;   // 8192
  const int NI   = in_sizes[3] / TAGS; // 40960
  const int E    = in_sizes[4];        // 1572864
  const int B    = in_sizes[7] / 2;    // 131072

  size_t rowsz = (size_t)N * 128 * sizeof(float);
  char* ws = (char*)d_ws;
  float* xt  = (float*)(ws);               // layer0 input; reused as layer-3 out
  float* b1  = (float*)(ws + rowsz);       // layer1 out; later aliased by h
  float* b2  = (float*)(ws + 2 * rowsz);   // layer2 out
  float* gkg = (float*)(ws + 3 * rowsz);   // TAGS x 64
  size_t o = 3 * rowsz + (size_t)TAGS * 64 * sizeof(float);
  int* off = (int*)(ws + o);  o += (size_t)(N + 1) * sizeof(int);
  int* pos = (int*)(ws + o);  o += (size_t)N * sizeof(int);
  o = (o + 7) & ~(size_t)7;
  int2* rec = (int2*)(ws + o);             // E records (src, w)
  float* h = b1;                           // expmap output, in-place over b1

  // CSR build
  hipMemsetAsync(pos, 0, (size_t)N * sizeof(int), stream);
  k_hist<<<(E + 255) / 256, 256, 0, stream>>>(edst, pos, E);
  k_scan<<<1, 1024, 0, stream>>>(pos, off, N);
  k_scatter<<<(E + 255) / 256, 256, 0, stream>>>(esrc, edst, ew, pos, rec, E);

  // feature prep
  k_node_prep<<<(N + 3) / 4, 256, 0, stream>>>(emb, ugr, xt, N, NU);
  k_tag_prep<<<(TAGS + 3) / 4, 256, 0, stream>>>(Tw, gkg, TAGS);
  k_hyper<<<NI / 64, 256, 0, stream>>>(sps, gkg, xt, NI, NU);

  // 3 encoder layers (gather-side, no atomics)
  k_gather<<<(N + 3) / 4, 256, 0, stream>>>(xt, b1, off, rec, N);
  k_gather<<<(N + 3) / 4, 256, 0, stream>>>(b1, b2, off, rec, N);
  k_gather<<<(N + 3) / 4, 256, 0, stream>>>(b2, xt, off, rec, N);

  k_expmap<<<(N + 3) / 4, 256, 0, stream>>>(b1, b2, xt, h, N);
  k_score<<<(B + 3) / 4, 256, 0, stream>>>(h, idx, out, B);
}

// Round 4
// 780.385 us; speedup vs baseline: 5.4131x; 1.0227x over previous
//
#include <hip/hip_runtime.h>

// TaxoRec forward pipeline on MI355X — round 4.
// Node feature rows padded to 128 f32 (512 B): cols 0..62 enc1, 63..125 enc2.
// Edge segment-sum via CSR + gather-side register reduction (no f32 atomics);
// gather reads 2 edges/iteration via half-wave float4 loads.
// hyper_agg: K-split tiled GEMM (64x64 tile, K=256/block, 4 partials) +
// combine kernel that sums partials and applies k2p->p2l->logmap0.

#define KSPLIT 4

__device__ __forceinline__ float wsum(float v) {
#pragma unroll
  for (int m = 32; m; m >>= 1) v += __shfl_xor(v, m, 64);
  return v;
}

__device__ __forceinline__ float logmap_scale(float ss) {
  float x0 = sqrtf(1.0f + ss);
  float alpha = fmaxf(x0, 1.0f + 1e-7f);
  float rnorm = sqrtf(fmaxf(ss, 1e-15f));
  return acoshf(alpha) / rnorm;
}

// xt[n,0:63) = logmap0(projx(emb[n])); rows < NU also get cols 63..125 from ugr.
__global__ __launch_bounds__(256) void k_node_prep(
    const float* __restrict__ emb, const float* __restrict__ ugr,
    float* __restrict__ xt, int N, int NU) {
  int n = blockIdx.x * 4 + (threadIdx.x >> 6);
  if (n >= N) return;
  int lane = threadIdx.x & 63;
  size_t base = (size_t)n * 128;
  float r1 = (lane < 63) ? emb[(size_t)n * 64 + 1 + lane] : 0.0f;
  float sc1 = logmap_scale(wsum(r1 * r1));
  if (lane < 63) xt[base + lane] = sc1 * r1;
  if (lane == 63) { xt[base + 126] = 0.0f; xt[base + 127] = 0.0f; }
  if (n < NU) {
    float r2 = (lane < 63) ? ugr[(size_t)n * 64 + 1 + lane] : 0.0f;
    float sc2 = logmap_scale(wsum(r2 * r2));
    if (lane < 63) xt[base + 63 + lane] = sc2 * r2;
  }
}

// per tag: gkg[t, 0:63) = gamma * k, gkg[t, 63] = gamma
__global__ __launch_bounds__(256) void k_tag_prep(
    const float* __restrict__ Tw, float* __restrict__ gkg, int TAGS) {
  int t = blockIdx.x * 4 + (threadIdx.x >> 6);
  if (t >= TAGS) return;
  int lane = threadIdx.x & 63;
  float r = (lane < 63) ? Tw[(size_t)t * 64 + 1 + lane] : 0.0f;
  float ss = wsum(r * r);
  float x0 = sqrtf(1.0f + ss);
  float p = r / (x0 + 1.0f);          // l2p (sk = 1)
  float sp = wsum(p * p);
  float k = 2.0f * p / (1.0f + sp);   // p2k
  float sk2 = wsum(k * k);
  float gamma = 1.0f / sqrtf(fmaxf(1.0f - sk2, 1e-15f));
  gkg[(size_t)t * 64 + lane] = (lane < 63) ? gamma * k : gamma;
}

// hyper_agg GEMM, K-split: block (bx, ksp) computes partial[ksp][64 items][64
// dims] over tags [ksp*256, ksp*256+256). 256 thr, 4x4 acc per thread.
__global__ __launch_bounds__(256) void k_hyper(
    const float* __restrict__ sps, const float* __restrict__ gkg,
    float* __restrict__ pb, int NI) {
  __shared__ float s_tile[64][36];   // [item][tag in 32-chunk], +4 pad
  __shared__ float g_tile[32][64];   // [tag][dim]
  int tid = threadIdx.x;
  int tx = tid & 15, ty = tid >> 4;  // compute mapping: dims / items
  int sx = tid & 7,  sy = tid >> 3;  // s staging: 8 float4-cols x 32 rows
  int gx = tid & 15, gy = tid >> 4;  // g staging: 16 float4-cols x 16 rows
  int ib = blockIdx.x * 64;
  int kbase = blockIdx.y * 256;      // this block's tag range
  float acc[4][4];
#pragma unroll
  for (int c = 0; c < 4; ++c)
#pragma unroll
    for (int d = 0; d < 4; ++d) acc[c][d] = 0.0f;

  const float4* sps4 = (const float4*)sps;
  const float4* gkg4 = (const float4*)gkg;

  for (int kc = 0; kc < 8; ++kc) {   // 8 chunks of 32 tags
    int t4b = (kbase >> 2) + kc * 8; // float4 col base into sps row
#pragma unroll
    for (int r = 0; r < 2; ++r) {
      int row = sy + 32 * r;
      *(float4*)&s_tile[row][sx * 4] = sps4[(size_t)(ib + row) * 256 + t4b + sx];
      int grow = gy + 16 * r;
      *(float4*)&g_tile[grow][gx * 4] =
          gkg4[(size_t)(kbase + kc * 32 + grow) * 16 + gx];
    }
    __syncthreads();
#pragma unroll
    for (int tg = 0; tg < 8; ++tg) {
      float4 s4[4], g4[4];
#pragma unroll
      for (int c = 0; c < 4; ++c) s4[c] = *(const float4*)&s_tile[ty * 4 + c][tg * 4];
#pragma unroll
      for (int j = 0; j < 4; ++j) g4[j] = *(const float4*)&g_tile[tg * 4 + j][tx * 4];
#pragma unroll
      for (int c = 0; c < 4; ++c) {
        float sv[4] = {s4[c].x, s4[c].y, s4[c].z, s4[c].w};
#pragma unroll
        for (int j = 0; j < 4; ++j) {
          acc[c][0] = fmaf(sv[j], g4[j].x, acc[c][0]);
          acc[c][1] = fmaf(sv[j], g4[j].y, acc[c][1]);
          acc[c][2] = fmaf(sv[j], g4[j].z, acc[c][2]);
          acc[c][3] = fmaf(sv[j], g4[j].w, acc[c][3]);
        }
      }
    }
    __syncthreads();
  }

  float* dst = pb + ((size_t)blockIdx.y * NI + ib) * 64;
#pragma unroll
  for (int c = 0; c < 4; ++c)
    *(float4*)&dst[(size_t)(ty * 4 + c) * 64 + tx * 4] =
        make_float4(acc[c][0], acc[c][1], acc[c][2], acc[c][3]);
}

// sum the KSPLIT partials, then k2p -> p2l -> logmap0; wave per item.
__global__ __launch_bounds__(256) void k_combine(
    const float* __restrict__ pb, float* __restrict__ xt, int NI, int NU) {
  int i = blockIdx.x * 4 + (threadIdx.x >> 6);
  if (i >= NI) return;
  int lane = threadIdx.x & 63;
  float v = 0.0f;
#pragma unroll
  for (int s = 0; s < KSPLIT; ++s) v += pb[((size_t)s * NI + i) * 64 + lane];
  float den = fmaxf(__shfl(v, 63, 64), 1e-15f);
  float y = v / den;
  float sy = wsum((lane < 63) ? y * y : 0.0f);
  float dk = 1.0f + sqrtf(fmaxf(1.0f - sy, 1e-15f));   // k2p denom
  float q = y / dk;
  float nq = wsum((lane < 63) ? q * q : 0.0f);
  float f = 1.0f / (1.0f - nq + 1e-6f);                // p2l
  float row0 = (1.0f + nq) * f;
  float r = 2.0f * q * f;
  float srr = wsum((lane < 63) ? r * r : 0.0f);
  float alpha = fmaxf(row0, 1.0f + 1e-7f);             // logmap0
  float scale = acoshf(alpha) / sqrtf(fmaxf(srr, 1e-15f));
  if (lane < 63)
    xt[(size_t)(NU + i) * 128 + 63 + lane] = scale * r;
}

// ---- CSR build ----------------------------------------------------------

__global__ __launch_bounds__(256) void k_hist(
    const int* __restrict__ edst, int* __restrict__ pos, int E) {
  int e = blockIdx.x * blockDim.x + threadIdx.x;
  if (e < E) atomicAdd(&pos[edst[e]], 1);
}

__global__ __launch_bounds__(1024) void k_scan(
    int* pos, int* __restrict__ off, int N) {
  __shared__ int part[1024];
  int t = threadIdx.x;
  int chunk = (N + 1023) >> 10;
  int beg = t * chunk, end = min(beg + chunk, N);
  int s = 0;
  for (int i = beg; i < end; ++i) s += pos[i];
  part[t] = s;
  __syncthreads();
  for (int d = 1; d < 1024; d <<= 1) {
    int v = (t >= d) ? part[t - d] : 0;
    __syncthreads();
    part[t] += v;
    __syncthreads();
  }
  int run = (t == 0) ? 0 : part[t - 1];
  for (int i = beg; i < end; ++i) {
    int dg = pos[i];
    off[i] = run;
    pos[i] = run;
    run += dg;
  }
  if (t == 1023) off[N] = run;
}

__global__ __launch_bounds__(256) void k_scatter(
    const int* __restrict__ esrc, const int* __restrict__ edst,
    const float* __restrict__ ew, int* __restrict__ pos,
    int2* __restrict__ rec, int E) {
  int e = blockIdx.x * blockDim.x + threadIdx.x;
  if (e >= E) return;
  int p = atomicAdd(&pos[edst[e]], 1);
  rec[p] = make_int2(esrc[e], __float_as_int(ew[e]));
}

// ---- one encoder layer: gather-side segment-sum -------------------------
// wave per dst node; 2 edges per iteration via half-wave float4 row loads.
__global__ __launch_bounds__(256) void k_gather(
    const float* __restrict__ cur, float* __restrict__ nxt,
    const int* __restrict__ off, const int2* __restrict__ rec, int N) {
  int n = blockIdx.x * 4 + (threadIdx.x >> 6);
  if (n >= N) return;
  int lane = threadIdx.x & 63;
  int half = lane >> 5;      // which edge of the pair this lane serves
  int q = lane & 31;         // float4 chunk within the 512 B row
  int beg = off[n], end = off[n + 1];
  float4 acc = make_float4(0.0f, 0.0f, 0.0f, 0.0f);
  for (int j = beg; j < end; j += 64) {
    int cnt = min(64, end - j);
    int sv = 0; float wv = 0.0f;
    if (lane < cnt) {
      int2 rc = rec[j + lane];
      sv = rc.x;
      wv = __int_as_float(rc.y);
    }
    int k = 0;
    for (; k + 2 <= cnt; k += 2) {
      int e = k + half;
      int s = __shfl(sv, e, 64);
      float w = __shfl(wv, e, 64);
      float4 v = ((const float4*)(cur + (size_t)s * 128))[q];
      acc.x = fmaf(w, v.x, acc.x);
      acc.y = fmaf(w, v.y, acc.y);
      acc.z = fmaf(w, v.z, acc.z);
      acc.w = fmaf(w, v.w, acc.w);
    }
    if (k < cnt) {           // odd leftover edge: half 0 handles it
      int s = __shfl(sv, k, 64);
      float w = __shfl(wv, k, 64);
      if (half == 0) {
        float4 v = ((const float4*)(cur + (size_t)s * 128))[q];
        acc.x = fmaf(w, v.x, acc.x);
        acc.y = fmaf(w, v.y, acc.y);
        acc.z = fmaf(w, v.z, acc.z);
        acc.w = fmaf(w, v.w, acc.w);
      }
    }
  }
  acc.x += __shfl_xor(acc.x, 32, 64);
  acc.y += __shfl_xor(acc.y, 32, 64);
  acc.z += __shfl_xor(acc.z, 32, 64);
  acc.w += __shfl_xor(acc.w, 32, 64);
  if (half == 0) ((float4*)(nxt + (size_t)n * 128))[q] = acc;
}

// h[n] = [expmap0(acc_enc1) | expmap0(acc_enc2)]; h aliases n1 (in-place).
__global__ __launch_bounds__(256) void k_expmap(
    const float* n1, const float* n2, const float* n3, float* h, int N) {
  int n = blockIdx.x * 4 + (threadIdx.x >> 6);
  if (n >= N) return;
  int lane = threadIdx.x & 63;
  size_t b = (size_t)n * 128;
  float a0 = 0.0f, a1 = 0.0f;
  if (lane < 63) {
    a0 = n1[b + lane] + n2[b + lane] + n3[b + lane];
    a1 = n1[b + 63 + lane] + n2[b + 63 + lane] + n3[b + 63 + lane];
  }
  float ss0 = wsum(a0 * a0), ss1 = wsum(a1 * a1);
  float nn0 = sqrtf(fmaxf(ss0, 1e-15f)), nn1 = sqrtf(fmaxf(ss1, 1e-15f));
  float s0 = sinhf(nn0) / nn0, s1 = sinhf(nn1) / nn1;
  if (lane < 63) {
    h[b + 1 + lane] = s0 * a0;
    h[b + 65 + lane] = s1 * a1;
  } else {
    h[b] = coshf(nn0);
    h[b + 64] = coshf(nn1);
  }
}

// out[b] = min(dist2(h[u,:64],h[v,:64]),50) + min(dist2(h[u,64:],h[v,64:]),15)
__global__ __launch_bounds__(256) void k_score(
    const float* __restrict__ h, const int* __restrict__ idx,
    float* __restrict__ out, int B) {
  int b = blockIdx.x * 4 + (threadIdx.x >> 6);
  if (b >= B) return;
  int lane = threadIdx.x & 63;
  int u = idx[2 * b], v = idx[2 * b + 1];
  float2 hu = ((const float2*)(h + (size_t)u * 128))[lane];
  float2 hv = ((const float2*)(h + (size_t)v * 128))[lane];
  float px = hu.x * hv.x;
  if (lane == 0 || lane == 32) px = -px;   // time components at cols 0 and 64
  float p = px + hu.y * hv.y;
#pragma unroll
  for (int m = 1; m < 32; m <<= 1) p += __shfl_xor(p, m, 64);  // per-half sums
  float dd = fmaxf(-p, 1.0f + 1e-7f);
  float a = acoshf(dd);
  float s = fminf(a * a, (lane < 32) ? 50.0f : 15.0f);
  s += __shfl_xor(s, 32, 64);
  if (lane == 0) out[b] = s;
}

extern "C" void kernel_launch(void* const* d_in, const int* in_sizes, int n_in,
                              void* d_out, int out_size, void* d_ws, size_t ws_size,
                              hipStream_t stream) {
  const float* emb = (const float*)d_in[0];
  const float* Tw  = (const float*)d_in[1];
  const float* ugr = (const float*)d_in[2];
  const float* sps = (const float*)d_in[3];
  const float* ew  = (const float*)d_in[4];
  const int* esrc  = (const int*)d_in[5];
  const int* edst  = (const int*)d_in[6];
  const int* idx   = (const int*)d_in[7];
  float* out = (float*)d_out;

  const int N    = in_sizes[0] / 64;   // 49152
  const int TAGS = in_sizes[1] / 64;   // 1024
  const int NU   = in_sizes[2] / 64;   // 8192
  const int NI   = in_sizes[3] / TAGS; // 40960
  const int E    = in_sizes[4];        // 1572864
  const int B    = in_sizes[7] / 2;    // 131072

  size_t rowsz = (size_t)N * 128 * sizeof(float);
  char* ws = (char*)d_ws;
  float* xt  = (float*)(ws);               // layer0 input; reused as layer-3 out
  float* b1  = (float*)(ws + rowsz);       // layer1 out; pb alias; h alias
  float* b2  = (float*)(ws + 2 * rowsz);   // layer2 out
  float* gkg = (float*)(ws + 3 * rowsz);   // TAGS x 64
  size_t o = 3 * rowsz + (size_t)TAGS * 64 * sizeof(float);
  int* off = (int*)(ws + o);  o += (size_t)(N + 1) * sizeof(int);
  int* pos = (int*)(ws + o);  o += (size_t)N * sizeof(int);
  o = (o + 7) & ~(size_t)7;
  int2* rec = (int2*)(ws + o);             // E records (src, w)
  float* pb = b1;   // KSPLIT x NI x 64 partials (42 MB) — dead before gathers
  float* h  = b1;   // expmap output, in-place over b1

  // CSR build
  hipMemsetAsync(pos, 0, (size_t)N * sizeof(int), stream);
  k_hist<<<(E + 255) / 256, 256, 0, stream>>>(edst, pos, E);
  k_scan<<<1, 1024, 0, stream>>>(pos, off, N);
  k_scatter<<<(E + 255) / 256, 256, 0, stream>>>(esrc, edst, ew, pos, rec, E);

  // feature prep
  k_node_prep<<<(N + 3) / 4, 256, 0, stream>>>(emb, ugr, xt, N, NU);
  k_tag_prep<<<(TAGS + 3) / 4, 256, 0, stream>>>(Tw, gkg, TAGS);
  dim3 hgrid(NI / 64, KSPLIT);
  k_hyper<<<hgrid, 256, 0, stream>>>(sps, gkg, pb, NI);
  k_combine<<<(NI + 3) / 4, 256, 0, stream>>>(pb, xt, NI, NU);

  // 3 encoder layers (gather-side, no atomics)
  k_gather<<<(N + 3) / 4, 256, 0, stream>>>(xt, b1, off, rec, N);
  k_gather<<<(N + 3) / 4, 256, 0, stream>>>(b1, b2, off, rec, N);
  k_gather<<<(N + 3) / 4, 256, 0, stream>>>(b2, xt, off, rec, N);

  k_expmap<<<(N + 3) / 4, 256, 0, stream>>>(b1, b2, xt, h, N);
  k_score<<<(B + 3) / 4, 256, 0, stream>>>(h, idx, out, B);
}

// Round 5
// 652.924 us; speedup vs baseline: 6.4698x; 1.1952x over previous
//
#include <hip/hip_runtime.h>

// TaxoRec forward pipeline on MI355X — round 5.
// Node feature rows padded to 128 f32 (512 B): cols 0..62 enc1, 63..125 enc2.
// CSR build: hist -> hierarchical scan (3 small kernels) -> radix-partition
// scatter (Pass A: LDS counting sort by dst>>9, coalesced staged writes;
// Pass B: bucket-local scatter to final CSR slots). No f32 atomics anywhere.
// hyper_agg: K-split tiled GEMM + combine (k2p->p2l->logmap0).

#define KSPLIT 4
#define NBUK 96          // N / 512

__device__ __forceinline__ float wsum(float v) {
#pragma unroll
  for (int m = 32; m; m >>= 1) v += __shfl_xor(v, m, 64);
  return v;
}

__device__ __forceinline__ float logmap_scale(float ss) {
  float x0 = sqrtf(1.0f + ss);
  float alpha = fmaxf(x0, 1.0f + 1e-7f);
  float rnorm = sqrtf(fmaxf(ss, 1e-15f));
  return acoshf(alpha) / rnorm;
}

// xt[n,0:63) = logmap0(projx(emb[n])); rows < NU also get cols 63..125 from ugr.
__global__ __launch_bounds__(256) void k_node_prep(
    const float* __restrict__ emb, const float* __restrict__ ugr,
    float* __restrict__ xt, int N, int NU) {
  int n = blockIdx.x * 4 + (threadIdx.x >> 6);
  if (n >= N) return;
  int lane = threadIdx.x & 63;
  size_t base = (size_t)n * 128;
  float r1 = (lane < 63) ? emb[(size_t)n * 64 + 1 + lane] : 0.0f;
  float sc1 = logmap_scale(wsum(r1 * r1));
  if (lane < 63) xt[base + lane] = sc1 * r1;
  if (lane == 63) { xt[base + 126] = 0.0f; xt[base + 127] = 0.0f; }
  if (n < NU) {
    float r2 = (lane < 63) ? ugr[(size_t)n * 64 + 1 + lane] : 0.0f;
    float sc2 = logmap_scale(wsum(r2 * r2));
    if (lane < 63) xt[base + 63 + lane] = sc2 * r2;
  }
}

// per tag: gkg[t, 0:63) = gamma * k, gkg[t, 63] = gamma
__global__ __launch_bounds__(256) void k_tag_prep(
    const float* __restrict__ Tw, float* __restrict__ gkg, int TAGS) {
  int t = blockIdx.x * 4 + (threadIdx.x >> 6);
  if (t >= TAGS) return;
  int lane = threadIdx.x & 63;
  float r = (lane < 63) ? Tw[(size_t)t * 64 + 1 + lane] : 0.0f;
  float ss = wsum(r * r);
  float x0 = sqrtf(1.0f + ss);
  float p = r / (x0 + 1.0f);          // l2p (sk = 1)
  float sp = wsum(p * p);
  float k = 2.0f * p / (1.0f + sp);   // p2k
  float sk2 = wsum(k * k);
  float gamma = 1.0f / sqrtf(fmaxf(1.0f - sk2, 1e-15f));
  gkg[(size_t)t * 64 + lane] = (lane < 63) ? gamma * k : gamma;
}

// hyper_agg GEMM, K-split: block (bx, ksp) computes partial[ksp][64][64].
__global__ __launch_bounds__(256) void k_hyper(
    const float* __restrict__ sps, const float* __restrict__ gkg,
    float* __restrict__ pb, int NI) {
  __shared__ float s_tile[64][36];
  __shared__ float g_tile[32][64];
  int tid = threadIdx.x;
  int tx = tid & 15, ty = tid >> 4;
  int sx = tid & 7,  sy = tid >> 3;
  int gx = tid & 15, gy = tid >> 4;
  int ib = blockIdx.x * 64;
  int kbase = blockIdx.y * 256;
  float acc[4][4];
#pragma unroll
  for (int c = 0; c < 4; ++c)
#pragma unroll
    for (int d = 0; d < 4; ++d) acc[c][d] = 0.0f;

  const float4* sps4 = (const float4*)sps;
  const float4* gkg4 = (const float4*)gkg;

  for (int kc = 0; kc < 8; ++kc) {
    int t4b = (kbase >> 2) + kc * 8;
#pragma unroll
    for (int r = 0; r < 2; ++r) {
      int row = sy + 32 * r;
      *(float4*)&s_tile[row][sx * 4] = sps4[(size_t)(ib + row) * 256 + t4b + sx];
      int grow = gy + 16 * r;
      *(float4*)&g_tile[grow][gx * 4] =
          gkg4[(size_t)(kbase + kc * 32 + grow) * 16 + gx];
    }
    __syncthreads();
#pragma unroll
    for (int tg = 0; tg < 8; ++tg) {
      float4 s4[4], g4[4];
#pragma unroll
      for (int c = 0; c < 4; ++c) s4[c] = *(const float4*)&s_tile[ty * 4 + c][tg * 4];
#pragma unroll
      for (int j = 0; j < 4; ++j) g4[j] = *(const float4*)&g_tile[tg * 4 + j][tx * 4];
#pragma unroll
      for (int c = 0; c < 4; ++c) {
        float sv[4] = {s4[c].x, s4[c].y, s4[c].z, s4[c].w};
#pragma unroll
        for (int j = 0; j < 4; ++j) {
          acc[c][0] = fmaf(sv[j], g4[j].x, acc[c][0]);
          acc[c][1] = fmaf(sv[j], g4[j].y, acc[c][1]);
          acc[c][2] = fmaf(sv[j], g4[j].z, acc[c][2]);
          acc[c][3] = fmaf(sv[j], g4[j].w, acc[c][3]);
        }
      }
    }
    __syncthreads();
  }

  float* dst = pb + ((size_t)blockIdx.y * NI + ib) * 64;
#pragma unroll
  for (int c = 0; c < 4; ++c)
    *(float4*)&dst[(size_t)(ty * 4 + c) * 64 + tx * 4] =
        make_float4(acc[c][0], acc[c][1], acc[c][2], acc[c][3]);
}

// sum the KSPLIT partials, then k2p -> p2l -> logmap0; wave per item.
__global__ __launch_bounds__(256) void k_combine(
    const float* __restrict__ pb, float* __restrict__ xt, int NI, int NU) {
  int i = blockIdx.x * 4 + (threadIdx.x >> 6);
  if (i >= NI) return;
  int lane = threadIdx.x & 63;
  float v = 0.0f;
#pragma unroll
  for (int s = 0; s < KSPLIT; ++s) v += pb[((size_t)s * NI + i) * 64 + lane];
  float den = fmaxf(__shfl(v, 63, 64), 1e-15f);
  float y = v / den;
  float sy = wsum((lane < 63) ? y * y : 0.0f);
  float dk = 1.0f + sqrtf(fmaxf(1.0f - sy, 1e-15f));
  float q = y / dk;
  float nq = wsum((lane < 63) ? q * q : 0.0f);
  float f = 1.0f / (1.0f - nq + 1e-6f);
  float row0 = (1.0f + nq) * f;
  float r = 2.0f * q * f;
  float srr = wsum((lane < 63) ? r * r : 0.0f);
  float alpha = fmaxf(row0, 1.0f + 1e-7f);
  float scale = acoshf(alpha) / sqrtf(fmaxf(srr, 1e-15f));
  if (lane < 63)
    xt[(size_t)(NU + i) * 128 + 63 + lane] = scale * r;
}

// ---- CSR build ----------------------------------------------------------

__global__ __launch_bounds__(256) void k_hist(
    const int* __restrict__ edst, int* __restrict__ pos, int E) {
  int e = blockIdx.x * blockDim.x + threadIdx.x;
  if (e < E) atomicAdd(&pos[edst[e]], 1);
}

// hierarchical scan: kb1 block-reduce, kb2 scan block sums, kb3 apply.
__global__ __launch_bounds__(256) void kb1(const int* __restrict__ pos,
                                           int* __restrict__ bsum) {
  __shared__ int red[4];
  int v = pos[blockIdx.x * 256 + threadIdx.x];
#pragma unroll
  for (int m = 32; m; m >>= 1) v += __shfl_xor(v, m, 64);
  if ((threadIdx.x & 63) == 0) red[threadIdx.x >> 6] = v;
  __syncthreads();
  if (threadIdx.x == 0) bsum[blockIdx.x] = red[0] + red[1] + red[2] + red[3];
}

__global__ __launch_bounds__(256) void kb2(const int* __restrict__ bsum,
                                           int* __restrict__ bof,
                                           int* __restrict__ off,
                                           int NB, int N, int E) {
  __shared__ int sc[256];
  int t = threadIdx.x;
  int mine = (t < NB) ? bsum[t] : 0;
  sc[t] = mine;
  __syncthreads();
  for (int d = 1; d < 256; d <<= 1) {
    int v = (t >= d) ? sc[t - d] : 0;
    __syncthreads();
    sc[t] += v;
    __syncthreads();
  }
  if (t < NB) bof[t] = sc[t] - mine;   // exclusive
  if (t == 0) off[N] = E;
}

__global__ __launch_bounds__(256) void kb3(int* pos, int* __restrict__ off,
                                           const int* __restrict__ bof) {
  __shared__ int sc[256];
  int t = threadIdx.x;
  int i = blockIdx.x * 256 + t;
  int d = pos[i];
  sc[t] = d;
  __syncthreads();
  for (int s = 1; s < 256; s <<= 1) {
    int v = (t >= s) ? sc[t - s] : 0;
    __syncthreads();
    sc[t] += v;
    __syncthreads();
  }
  int val = bof[blockIdx.x] + sc[t] - d;
  off[i] = val;
  pos[i] = val;
}

// Pass A: radix partition edges by bucket = dst>>9 into staged runs.
// Block: 2048 edges, LDS counting sort, coalesced run writes at bucket
// frontiers (reserved via one atomic per bucket per block).
__global__ __launch_bounds__(256) void k_passA(
    const int* __restrict__ esrc, const int* __restrict__ edst,
    const float* __restrict__ ew, const int* __restrict__ off,
    int* __restrict__ bcur, int2* __restrict__ stage) {
  __shared__ int lh[128];
  __shared__ int lscan[128];
  __shared__ int lcur[128];
  __shared__ int gb[128];
  __shared__ unsigned int keyb[2048];
  __shared__ float wvb[2048];
  int tid = threadIdx.x;
  int base = blockIdx.x * 2048;
  if (tid < 128) lh[tid] = 0;
  __syncthreads();
  unsigned int key[8]; float wv[8];
#pragma unroll
  for (int r = 0; r < 8; ++r) {
    int e = base + r * 256 + tid;
    int d = edst[e];
    key[r] = ((unsigned int)d << 16) | (unsigned int)esrc[e];
    wv[r] = ew[e];
    atomicAdd(&lh[d >> 9], 1);
  }
  __syncthreads();
  if (tid < 128) lscan[tid] = lh[tid];
  __syncthreads();
  for (int d = 1; d < 128; d <<= 1) {
    int v = (tid < 128 && tid >= d) ? lscan[tid - d] : 0;
    __syncthreads();
    if (tid < 128) lscan[tid] += v;
    __syncthreads();
  }
  if (tid < 128) {
    int excl = lscan[tid] - lh[tid];
    lscan[tid] = excl;
    lcur[tid] = 0;
    if (tid < NBUK && lh[tid] > 0)
      gb[tid] = off[tid << 9] + atomicAdd(&bcur[tid], lh[tid]);
  }
  __syncthreads();
#pragma unroll
  for (int r = 0; r < 8; ++r) {
    int b = key[r] >> 25;
    int lp = lscan[b] + atomicAdd(&lcur[b], 1);
    keyb[lp] = key[r];
    wvb[lp] = wv[r];
  }
  __syncthreads();
#pragma unroll
  for (int r = 0; r < 8; ++r) {
    int i = r * 256 + tid;
    unsigned int k2 = keyb[i];
    int b = k2 >> 25;
    stage[gb[b] + (i - lscan[b])] = make_int2((int)k2, __float_as_int(wvb[i]));
  }
}

// Pass B: per-bucket scatter of staged records to final CSR slots.
// Bucket's output region (~130 KB) stays cache-resident while active.
__global__ __launch_bounds__(256) void k_passB(
    const int2* __restrict__ stage, const int* __restrict__ off,
    int* __restrict__ pos, int2* __restrict__ rec) {
  int b = blockIdx.x >> 3, part = blockIdx.x & 7;
  int bb = off[b << 9], be = off[(b + 1) << 9];
  int len = be - bb;
  int pbeg = bb + (len * part >> 3);
  int pend = bb + (len * (part + 1) >> 3);
  for (int i = pbeg + threadIdx.x; i < pend; i += 256) {
    int2 r = stage[i];
    unsigned int k2 = (unsigned int)r.x;
    int d = (int)(k2 >> 16);
    int p = atomicAdd(&pos[d], 1);
    rec[p] = make_int2((int)(k2 & 0xFFFF), r.y);
  }
}

// ---- one encoder layer: gather-side segment-sum -------------------------
__global__ __launch_bounds__(256) void k_gather(
    const float* __restrict__ cur, float* __restrict__ nxt,
    const int* __restrict__ off, const int2* __restrict__ rec, int N) {
  int n = blockIdx.x * 4 + (threadIdx.x >> 6);
  if (n >= N) return;
  int lane = threadIdx.x & 63;
  int half = lane >> 5;
  int q = lane & 31;
  int beg = off[n], end = off[n + 1];
  float4 acc = make_float4(0.0f, 0.0f, 0.0f, 0.0f);
  for (int j = beg; j < end; j += 64) {
    int cnt = min(64, end - j);
    int sv = 0; float wv = 0.0f;
    if (lane < cnt) {
      int2 rc = rec[j + lane];
      sv = rc.x;
      wv = __int_as_float(rc.y);
    }
    int k = 0;
    for (; k + 2 <= cnt; k += 2) {
      int e = k + half;
      int s = __shfl(sv, e, 64);
      float w = __shfl(wv, e, 64);
      float4 v = ((const float4*)(cur + (size_t)s * 128))[q];
      acc.x = fmaf(w, v.x, acc.x);
      acc.y = fmaf(w, v.y, acc.y);
      acc.z = fmaf(w, v.z, acc.z);
      acc.w = fmaf(w, v.w, acc.w);
    }
    if (k < cnt) {
      int s = __shfl(sv, k, 64);
      float w = __shfl(wv, k, 64);
      if (half == 0) {
        float4 v = ((const float4*)(cur + (size_t)s * 128))[q];
        acc.x = fmaf(w, v.x, acc.x);
        acc.y = fmaf(w, v.y, acc.y);
        acc.z = fmaf(w, v.z, acc.z);
        acc.w = fmaf(w, v.w, acc.w);
      }
    }
  }
  acc.x += __shfl_xor(acc.x, 32, 64);
  acc.y += __shfl_xor(acc.y, 32, 64);
  acc.z += __shfl_xor(acc.z, 32, 64);
  acc.w += __shfl_xor(acc.w, 32, 64);
  if (half == 0) ((float4*)(nxt + (size_t)n * 128))[q] = acc;
}

// h[n] = [expmap0(acc_enc1) | expmap0(acc_enc2)]; h aliases n1 (in-place).
__global__ __launch_bounds__(256) void k_expmap(
    const float* n1, const float* n2, const float* n3, float* h, int N) {
  int n = blockIdx.x * 4 + (threadIdx.x >> 6);
  if (n >= N) return;
  int lane = threadIdx.x & 63;
  size_t b = (size_t)n * 128;
  float a0 = 0.0f, a1 = 0.0f;
  if (lane < 63) {
    a0 = n1[b + lane] + n2[b + lane] + n3[b + lane];
    a1 = n1[b + 63 + lane] + n2[b + 63 + lane] + n3[b + 63 + lane];
  }
  float ss0 = wsum(a0 * a0), ss1 = wsum(a1 * a1);
  float nn0 = sqrtf(fmaxf(ss0, 1e-15f)), nn1 = sqrtf(fmaxf(ss1, 1e-15f));
  float s0 = sinhf(nn0) / nn0, s1 = sinhf(nn1) / nn1;
  if (lane < 63) {
    h[b + 1 + lane] = s0 * a0;
    h[b + 65 + lane] = s1 * a1;
  } else {
    h[b] = coshf(nn0);
    h[b + 64] = coshf(nn1);
  }
}

// out[b] = min(dist2(h[u,:64],h[v,:64]),50) + min(dist2(h[u,64:],h[v,64:]),15)
__global__ __launch_bounds__(256) void k_score(
    const float* __restrict__ h, const int* __restrict__ idx,
    float* __restrict__ out, int B) {
  int b = blockIdx.x * 4 + (threadIdx.x >> 6);
  if (b >= B) return;
  int lane = threadIdx.x & 63;
  int u = idx[2 * b], v = idx[2 * b + 1];
  float2 hu = ((const float2*)(h + (size_t)u * 128))[lane];
  float2 hv = ((const float2*)(h + (size_t)v * 128))[lane];
  float px = hu.x * hv.x;
  if (lane == 0 || lane == 32) px = -px;
  float p = px + hu.y * hv.y;
#pragma unroll
  for (int m = 1; m < 32; m <<= 1) p += __shfl_xor(p, m, 64);
  float dd = fmaxf(-p, 1.0f + 1e-7f);
  float a = acoshf(dd);
  float s = fminf(a * a, (lane < 32) ? 50.0f : 15.0f);
  s += __shfl_xor(s, 32, 64);
  if (lane == 0) out[b] = s;
}

extern "C" void kernel_launch(void* const* d_in, const int* in_sizes, int n_in,
                              void* d_out, int out_size, void* d_ws, size_t ws_size,
                              hipStream_t stream) {
  const float* emb = (const float*)d_in[0];
  const float* Tw  = (const float*)d_in[1];
  const float* ugr = (const float*)d_in[2];
  const float* sps = (const float*)d_in[3];
  const float* ew  = (const float*)d_in[4];
  const int* esrc  = (const int*)d_in[5];
  const int* edst  = (const int*)d_in[6];
  const int* idx   = (const int*)d_in[7];
  float* out = (float*)d_out;

  const int N    = in_sizes[0] / 64;   // 49152
  const int TAGS = in_sizes[1] / 64;   // 1024
  const int NU   = in_sizes[2] / 64;   // 8192
  const int NI   = in_sizes[3] / TAGS; // 40960
  const int E    = in_sizes[4];        // 1572864
  const int B    = in_sizes[7] / 2;    // 131072
  const int NB   = N / 256;            // 192 scan blocks

  size_t rowsz = (size_t)N * 128 * sizeof(float);
  char* ws = (char*)d_ws;
  float* xt  = (float*)(ws);               // layer0 input; reused as layer-3 out
  float* b1  = (float*)(ws + rowsz);       // layer1 out; pb alias; h alias
  float* b2  = (float*)(ws + 2 * rowsz);   // layer2 out; stage alias
  float* gkg = (float*)(ws + 3 * rowsz);   // TAGS x 64
  size_t o = 3 * rowsz + (size_t)TAGS * 64 * sizeof(float);
  int* off  = (int*)(ws + o);  o += (size_t)(N + 1) * sizeof(int);
  int* pos  = (int*)(ws + o);  o += (size_t)N * sizeof(int);
  int* bsum = (int*)(ws + o);  o += (size_t)NB * sizeof(int);
  int* bof  = (int*)(ws + o);  o += (size_t)NB * sizeof(int);
  int* bcur = (int*)(ws + o);  o += (size_t)NBUK * sizeof(int);
  o = (o + 7) & ~(size_t)7;
  int2* rec = (int2*)(ws + o);             // E records (src, w)
  int2* stage = (int2*)b2;                 // E staged records (dead until gather2)
  float* pb = b1;                          // KSPLIT x NI x 64 partials
  float* h  = b1;                          // expmap output, in-place over b1

  // CSR build
  hipMemsetAsync(pos, 0, (size_t)N * sizeof(int), stream);
  hipMemsetAsync(bcur, 0, (size_t)NBUK * sizeof(int), stream);
  k_hist<<<(E + 255) / 256, 256, 0, stream>>>(edst, pos, E);
  kb1<<<NB, 256, 0, stream>>>(pos, bsum);
  kb2<<<1, 256, 0, stream>>>(bsum, bof, off, NB, N, E);
  kb3<<<NB, 256, 0, stream>>>(pos, off, bof);
  k_passA<<<E / 2048, 256, 0, stream>>>(esrc, edst, ew, off, bcur, stage);
  k_passB<<<NBUK * 8, 256, 0, stream>>>(stage, off, pos, rec);

  // feature prep
  k_node_prep<<<(N + 3) / 4, 256, 0, stream>>>(emb, ugr, xt, N, NU);
  k_tag_prep<<<(TAGS + 3) / 4, 256, 0, stream>>>(Tw, gkg, TAGS);
  dim3 hgrid(NI / 64, KSPLIT);
  k_hyper<<<hgrid, 256, 0, stream>>>(sps, gkg, pb, NI);
  k_combine<<<(NI + 3) / 4, 256, 0, stream>>>(pb, xt, NI, NU);

  // 3 encoder layers (gather-side, no atomics)
  k_gather<<<(N + 3) / 4, 256, 0, stream>>>(xt, b1, off, rec, N);
  k_gather<<<(N + 3) / 4, 256, 0, stream>>>(b1, b2, off, rec, N);
  k_gather<<<(N + 3) / 4, 256, 0, stream>>>(b2, xt, off, rec, N);

  k_expmap<<<(N + 3) / 4, 256, 0, stream>>>(b1, b2, xt, h, N);
  k_score<<<(B + 3) / 4, 256, 0, stream>>>(h, idx, out, B);
}

// Round 6
// 629.890 us; speedup vs baseline: 6.7064x; 1.0366x over previous
//
#include <hip/hip_runtime.h>

// TaxoRec forward pipeline on MI355X — round 6.
// Node feature rows padded to 128 f32 (512 B): cols 0..62 enc1, 63..125 enc2.
// CSR build: hist -> hierarchical scan -> radix-partition scatter.
// Gather: 8-edge unrolled inner loop (4 row-loads in flight per half-wave).
// Layer 3 gather is fused with expmap (h written directly, k_expmap gone).
// hyper_agg: K-split tiled GEMM + combine (k2p->p2l->logmap0).

#define KSPLIT 4
#define NBUK 96          // N / 512

__device__ __forceinline__ float wsum(float v) {
#pragma unroll
  for (int m = 32; m; m >>= 1) v += __shfl_xor(v, m, 64);
  return v;
}

__device__ __forceinline__ float logmap_scale(float ss) {
  float x0 = sqrtf(1.0f + ss);
  float alpha = fmaxf(x0, 1.0f + 1e-7f);
  float rnorm = sqrtf(fmaxf(ss, 1e-15f));
  return acoshf(alpha) / rnorm;
}

// xt[n,0:63) = logmap0(projx(emb[n])); rows < NU also get cols 63..125 from ugr.
__global__ __launch_bounds__(256) void k_node_prep(
    const float* __restrict__ emb, const float* __restrict__ ugr,
    float* __restrict__ xt, int N, int NU) {
  int n = blockIdx.x * 4 + (threadIdx.x >> 6);
  if (n >= N) return;
  int lane = threadIdx.x & 63;
  size_t base = (size_t)n * 128;
  float r1 = (lane < 63) ? emb[(size_t)n * 64 + 1 + lane] : 0.0f;
  float sc1 = logmap_scale(wsum(r1 * r1));
  if (lane < 63) xt[base + lane] = sc1 * r1;
  if (lane == 63) { xt[base + 126] = 0.0f; xt[base + 127] = 0.0f; }
  if (n < NU) {
    float r2 = (lane < 63) ? ugr[(size_t)n * 64 + 1 + lane] : 0.0f;
    float sc2 = logmap_scale(wsum(r2 * r2));
    if (lane < 63) xt[base + 63 + lane] = sc2 * r2;
  }
}

// per tag: gkg[t, 0:63) = gamma * k, gkg[t, 63] = gamma
__global__ __launch_bounds__(256) void k_tag_prep(
    const float* __restrict__ Tw, float* __restrict__ gkg, int TAGS) {
  int t = blockIdx.x * 4 + (threadIdx.x >> 6);
  if (t >= TAGS) return;
  int lane = threadIdx.x & 63;
  float r = (lane < 63) ? Tw[(size_t)t * 64 + 1 + lane] : 0.0f;
  float ss = wsum(r * r);
  float x0 = sqrtf(1.0f + ss);
  float p = r / (x0 + 1.0f);          // l2p (sk = 1)
  float sp = wsum(p * p);
  float k = 2.0f * p / (1.0f + sp);   // p2k
  float sk2 = wsum(k * k);
  float gamma = 1.0f / sqrtf(fmaxf(1.0f - sk2, 1e-15f));
  gkg[(size_t)t * 64 + lane] = (lane < 63) ? gamma * k : gamma;
}

// hyper_agg GEMM, K-split: block (bx, ksp) computes partial[ksp][64][64].
__global__ __launch_bounds__(256) void k_hyper(
    const float* __restrict__ sps, const float* __restrict__ gkg,
    float* __restrict__ pb, int NI) {
  __shared__ float s_tile[64][36];
  __shared__ float g_tile[32][64];
  int tid = threadIdx.x;
  int tx = tid & 15, ty = tid >> 4;
  int sx = tid & 7,  sy = tid >> 3;
  int gx = tid & 15, gy = tid >> 4;
  int ib = blockIdx.x * 64;
  int kbase = blockIdx.y * 256;
  float acc[4][4];
#pragma unroll
  for (int c = 0; c < 4; ++c)
#pragma unroll
    for (int d = 0; d < 4; ++d) acc[c][d] = 0.0f;

  const float4* sps4 = (const float4*)sps;
  const float4* gkg4 = (const float4*)gkg;

  for (int kc = 0; kc < 8; ++kc) {
    int t4b = (kbase >> 2) + kc * 8;
#pragma unroll
    for (int r = 0; r < 2; ++r) {
      int row = sy + 32 * r;
      *(float4*)&s_tile[row][sx * 4] = sps4[(size_t)(ib + row) * 256 + t4b + sx];
      int grow = gy + 16 * r;
      *(float4*)&g_tile[grow][gx * 4] =
          gkg4[(size_t)(kbase + kc * 32 + grow) * 16 + gx];
    }
    __syncthreads();
#pragma unroll
    for (int tg = 0; tg < 8; ++tg) {
      float4 s4[4], g4[4];
#pragma unroll
      for (int c = 0; c < 4; ++c) s4[c] = *(const float4*)&s_tile[ty * 4 + c][tg * 4];
#pragma unroll
      for (int j = 0; j < 4; ++j) g4[j] = *(const float4*)&g_tile[tg * 4 + j][tx * 4];
#pragma unroll
      for (int c = 0; c < 4; ++c) {
        float sv[4] = {s4[c].x, s4[c].y, s4[c].z, s4[c].w};
#pragma unroll
        for (int j = 0; j < 4; ++j) {
          acc[c][0] = fmaf(sv[j], g4[j].x, acc[c][0]);
          acc[c][1] = fmaf(sv[j], g4[j].y, acc[c][1]);
          acc[c][2] = fmaf(sv[j], g4[j].z, acc[c][2]);
          acc[c][3] = fmaf(sv[j], g4[j].w, acc[c][3]);
        }
      }
    }
    __syncthreads();
  }

  float* dst = pb + ((size_t)blockIdx.y * NI + ib) * 64;
#pragma unroll
  for (int c = 0; c < 4; ++c)
    *(float4*)&dst[(size_t)(ty * 4 + c) * 64 + tx * 4] =
        make_float4(acc[c][0], acc[c][1], acc[c][2], acc[c][3]);
}

// sum the KSPLIT partials, then k2p -> p2l -> logmap0; wave per item.
__global__ __launch_bounds__(256) void k_combine(
    const float* __restrict__ pb, float* __restrict__ xt, int NI, int NU) {
  int i = blockIdx.x * 4 + (threadIdx.x >> 6);
  if (i >= NI) return;
  int lane = threadIdx.x & 63;
  float v = 0.0f;
#pragma unroll
  for (int s = 0; s < KSPLIT; ++s) v += pb[((size_t)s * NI + i) * 64 + lane];
  float den = fmaxf(__shfl(v, 63, 64), 1e-15f);
  float y = v / den;
  float sy = wsum((lane < 63) ? y * y : 0.0f);
  float dk = 1.0f + sqrtf(fmaxf(1.0f - sy, 1e-15f));
  float q = y / dk;
  float nq = wsum((lane < 63) ? q * q : 0.0f);
  float f = 1.0f / (1.0f - nq + 1e-6f);
  float row0 = (1.0f + nq) * f;
  float r = 2.0f * q * f;
  float srr = wsum((lane < 63) ? r * r : 0.0f);
  float alpha = fmaxf(row0, 1.0f + 1e-7f);
  float scale = acoshf(alpha) / sqrtf(fmaxf(srr, 1e-15f));
  if (lane < 63)
    xt[(size_t)(NU + i) * 128 + 63 + lane] = scale * r;
}

// ---- CSR build ----------------------------------------------------------

__global__ __launch_bounds__(256) void k_hist(
    const int* __restrict__ edst, int* __restrict__ pos, int E) {
  int e = blockIdx.x * blockDim.x + threadIdx.x;
  if (e < E) atomicAdd(&pos[edst[e]], 1);
}

__global__ __launch_bounds__(256) void kb1(const int* __restrict__ pos,
                                           int* __restrict__ bsum) {
  __shared__ int red[4];
  int v = pos[blockIdx.x * 256 + threadIdx.x];
#pragma unroll
  for (int m = 32; m; m >>= 1) v += __shfl_xor(v, m, 64);
  if ((threadIdx.x & 63) == 0) red[threadIdx.x >> 6] = v;
  __syncthreads();
  if (threadIdx.x == 0) bsum[blockIdx.x] = red[0] + red[1] + red[2] + red[3];
}

__global__ __launch_bounds__(256) void kb2(const int* __restrict__ bsum,
                                           int* __restrict__ bof,
                                           int* __restrict__ off,
                                           int NB, int N, int E) {
  __shared__ int sc[256];
  int t = threadIdx.x;
  int mine = (t < NB) ? bsum[t] : 0;
  sc[t] = mine;
  __syncthreads();
  for (int d = 1; d < 256; d <<= 1) {
    int v = (t >= d) ? sc[t - d] : 0;
    __syncthreads();
    sc[t] += v;
    __syncthreads();
  }
  if (t < NB) bof[t] = sc[t] - mine;   // exclusive
  if (t == 0) off[N] = E;
}

__global__ __launch_bounds__(256) void kb3(int* pos, int* __restrict__ off,
                                           const int* __restrict__ bof) {
  __shared__ int sc[256];
  int t = threadIdx.x;
  int i = blockIdx.x * 256 + t;
  int d = pos[i];
  sc[t] = d;
  __syncthreads();
  for (int s = 1; s < 256; s <<= 1) {
    int v = (t >= s) ? sc[t - s] : 0;
    __syncthreads();
    sc[t] += v;
    __syncthreads();
  }
  int val = bof[blockIdx.x] + sc[t] - d;
  off[i] = val;
  pos[i] = val;
}

// Pass A: radix partition edges by bucket = dst>>9 into staged runs.
__global__ __launch_bounds__(256) void k_passA(
    const int* __restrict__ esrc, const int* __restrict__ edst,
    const float* __restrict__ ew, const int* __restrict__ off,
    int* __restrict__ bcur, int2* __restrict__ stage) {
  __shared__ int lh[128];
  __shared__ int lscan[128];
  __shared__ int lcur[128];
  __shared__ int gb[128];
  __shared__ unsigned int keyb[2048];
  __shared__ float wvb[2048];
  int tid = threadIdx.x;
  int base = blockIdx.x * 2048;
  if (tid < 128) lh[tid] = 0;
  __syncthreads();
  unsigned int key[8]; float wv[8];
#pragma unroll
  for (int r = 0; r < 8; ++r) {
    int e = base + r * 256 + tid;
    int d = edst[e];
    key[r] = ((unsigned int)d << 16) | (unsigned int)esrc[e];
    wv[r] = ew[e];
    atomicAdd(&lh[d >> 9], 1);
  }
  __syncthreads();
  if (tid < 128) lscan[tid] = lh[tid];
  __syncthreads();
  for (int d = 1; d < 128; d <<= 1) {
    int v = (tid < 128 && tid >= d) ? lscan[tid - d] : 0;
    __syncthreads();
    if (tid < 128) lscan[tid] += v;
    __syncthreads();
  }
  if (tid < 128) {
    int excl = lscan[tid] - lh[tid];
    lscan[tid] = excl;
    lcur[tid] = 0;
    if (tid < NBUK && lh[tid] > 0)
      gb[tid] = off[tid << 9] + atomicAdd(&bcur[tid], lh[tid]);
  }
  __syncthreads();
#pragma unroll
  for (int r = 0; r < 8; ++r) {
    int b = key[r] >> 25;
    int lp = lscan[b] + atomicAdd(&lcur[b], 1);
    keyb[lp] = key[r];
    wvb[lp] = wv[r];
  }
  __syncthreads();
#pragma unroll
  for (int r = 0; r < 8; ++r) {
    int i = r * 256 + tid;
    unsigned int k2 = keyb[i];
    int b = k2 >> 25;
    stage[gb[b] + (i - lscan[b])] = make_int2((int)k2, __float_as_int(wvb[i]));
  }
}

// Pass B: per-bucket scatter of staged records to final CSR slots.
__global__ __launch_bounds__(256) void k_passB(
    const int2* __restrict__ stage, const int* __restrict__ off,
    int* __restrict__ pos, int2* __restrict__ rec) {
  int b = blockIdx.x >> 3, part = blockIdx.x & 7;
  int bb = off[b << 9], be = off[(b + 1) << 9];
  int len = be - bb;
  int pbeg = bb + (len * part >> 3);
  int pend = bb + (len * (part + 1) >> 3);
  for (int i = pbeg + threadIdx.x; i < pend; i += 256) {
    int2 r = stage[i];
    unsigned int k2 = (unsigned int)r.x;
    int d = (int)(k2 >> 16);
    int p = atomicAdd(&pos[d], 1);
    rec[p] = make_int2((int)(k2 & 0xFFFF), r.y);
  }
}

// ---- gather core: segment-sum row for dst n; 8 edges/iter, 4 loads in
// flight per half-wave. Returns merged row chunk (lane&31) in all lanes.
__device__ __forceinline__ float4 gather_row(
    const float* __restrict__ cur, const int* __restrict__ off,
    const int2* __restrict__ rec, int n, int lane) {
  int half = lane >> 5;
  int q = lane & 31;
  int beg = off[n], end = off[n + 1];
  float4 acc = make_float4(0.0f, 0.0f, 0.0f, 0.0f);
  for (int j = beg; j < end; j += 64) {
    int cnt = min(64, end - j);
    int sv = 0; float wv = 0.0f;
    if (lane < cnt) {
      int2 rc = rec[j + lane];
      sv = rc.x;
      wv = __int_as_float(rc.y);
    }
    int k = 0;
    for (; k + 8 <= cnt; k += 8) {
      int s[4]; float w[4]; float4 v[4];
#pragma unroll
      for (int u = 0; u < 4; ++u) {
        int e = k + 2 * u + half;
        s[u] = __shfl(sv, e, 64);
        w[u] = __shfl(wv, e, 64);
      }
#pragma unroll
      for (int u = 0; u < 4; ++u)
        v[u] = ((const float4*)(cur + (size_t)s[u] * 128))[q];
#pragma unroll
      for (int u = 0; u < 4; ++u) {
        acc.x = fmaf(w[u], v[u].x, acc.x);
        acc.y = fmaf(w[u], v[u].y, acc.y);
        acc.z = fmaf(w[u], v[u].z, acc.z);
        acc.w = fmaf(w[u], v[u].w, acc.w);
      }
    }
    for (; k + 2 <= cnt; k += 2) {
      int e = k + half;
      int s0 = __shfl(sv, e, 64);
      float w0 = __shfl(wv, e, 64);
      float4 v = ((const float4*)(cur + (size_t)s0 * 128))[q];
      acc.x = fmaf(w0, v.x, acc.x);
      acc.y = fmaf(w0, v.y, acc.y);
      acc.z = fmaf(w0, v.z, acc.z);
      acc.w = fmaf(w0, v.w, acc.w);
    }
    if (k < cnt) {
      int s0 = __shfl(sv, k, 64);
      float w0 = __shfl(wv, k, 64);
      if (half == 0) {
        float4 v = ((const float4*)(cur + (size_t)s0 * 128))[q];
        acc.x = fmaf(w0, v.x, acc.x);
        acc.y = fmaf(w0, v.y, acc.y);
        acc.z = fmaf(w0, v.z, acc.z);
        acc.w = fmaf(w0, v.w, acc.w);
      }
    }
  }
  acc.x += __shfl_xor(acc.x, 32, 64);
  acc.y += __shfl_xor(acc.y, 32, 64);
  acc.z += __shfl_xor(acc.z, 32, 64);
  acc.w += __shfl_xor(acc.w, 32, 64);
  return acc;
}

// layers 1,2: plain gather, write full row once.
__global__ __launch_bounds__(256) void k_gather(
    const float* __restrict__ cur, float* __restrict__ nxt,
    const int* __restrict__ off, const int2* __restrict__ rec, int N) {
  int n = blockIdx.x * 4 + (threadIdx.x >> 6);
  if (n >= N) return;
  int lane = threadIdx.x & 63;
  float4 acc = gather_row(cur, off, rec, n, lane);
  if (lane < 32) ((float4*)(nxt + (size_t)n * 128))[lane] = acc;
}

// layer 3 fused with expmap: h[n] = [expmap0(l3+b1+b2 enc1) | (enc2)].
// h aliases b1 (row n read by this wave only, before its write).
__global__ __launch_bounds__(256) void k_gather_exp(
    const float* __restrict__ cur, const float* b1, const float* __restrict__ b2,
    const int* __restrict__ off, const int2* __restrict__ rec,
    float* h, int N) {
  __shared__ float ld[4][128];
  int wid = threadIdx.x >> 6;
  int n0 = blockIdx.x * 4 + wid;
  int n = min(n0, N - 1);              // clamp: keep all waves at the barrier
  int lane = threadIdx.x & 63;
  int q = lane & 31;
  float4 a3 = gather_row(cur, off, rec, n, lane);
  size_t b = (size_t)n * 128;
  float4 r1 = ((const float4*)(b1 + b))[q];
  float4 r2 = ((const float4*)(b2 + b))[q];
  float4 a = make_float4(a3.x + r1.x + r2.x, a3.y + r1.y + r2.y,
                         a3.z + r1.z + r2.z, a3.w + r1.w + r2.w);
  // per-lane partial sums of squares, split at col 63 (cols 126/127 are 0)
  float vv[4] = {a.x, a.y, a.z, a.w};
  float p0 = 0.0f, p1 = 0.0f;
#pragma unroll
  for (int i = 0; i < 4; ++i) {
    int c = 4 * q + i;
    if (c < 63) p0 += vv[i] * vv[i]; else p1 += vv[i] * vv[i];
  }
  float ss0 = 0.5f * wsum(p0);         // chunks duplicated across halves
  float ss1 = 0.5f * wsum(p1);
  float nn0 = sqrtf(fmaxf(ss0, 1e-15f)), nn1 = sqrtf(fmaxf(ss1, 1e-15f));
  float s0 = sinhf(nn0) / nn0, s1 = sinhf(nn1) / nn1;
  if (lane < 32) {
    // h[c+1] = s0*a[c] (c<63); h[c+2] = s1*a[c] (63<=c<126); h[0],h[64]=cosh
#pragma unroll
    for (int i = 0; i < 4; ++i) {
      int c = 4 * q + i;
      if (c < 63) ld[wid][c + 1] = s0 * vv[i];
      else if (c < 126) ld[wid][c + 2] = s1 * vv[i];
    }
    if (q == 0) { ld[wid][0] = coshf(nn0); ld[wid][64] = coshf(nn1); }
  }
  __syncthreads();
  if (lane < 32 && n0 < N)
    ((float4*)(h + b))[q] = *(const float4*)&ld[wid][4 * q];
}

// out[b] = min(dist2(.,.),50) + min(dist2(.,.),15); 4 pairs per wave.
__global__ __launch_bounds__(256) void k_score(
    const float* __restrict__ h, const int* __restrict__ idx,
    float* __restrict__ out, int B) {
  int w = blockIdx.x * 4 + (threadIdx.x >> 6);
  int lane = threadIdx.x & 63;
  int b0 = w * 4;
  if (b0 >= B) return;
  int np = min(4, B - b0);
  float2 hu[4], hv[4];
#pragma unroll
  for (int p = 0; p < 4; ++p) {
    int bb = b0 + ((p < np) ? p : 0);
    int u = idx[2 * bb], v = idx[2 * bb + 1];
    hu[p] = ((const float2*)(h + (size_t)u * 128))[lane];
    hv[p] = ((const float2*)(h + (size_t)v * 128))[lane];
  }
#pragma unroll
  for (int p = 0; p < 4; ++p) {
    if (p >= np) break;
    float px = hu[p].x * hv[p].x;
    if (lane == 0 || lane == 32) px = -px;   // time comps at cols 0 and 64
    float pp = px + hu[p].y * hv[p].y;
#pragma unroll
    for (int m = 1; m < 32; m <<= 1) pp += __shfl_xor(pp, m, 64);
    float dd = fmaxf(-pp, 1.0f + 1e-7f);
    float a = acoshf(dd);
    float s = fminf(a * a, (lane < 32) ? 50.0f : 15.0f);
    s += __shfl_xor(s, 32, 64);
    if (lane == 0) out[b0 + p] = s;
  }
}

extern "C" void kernel_launch(void* const* d_in, const int* in_sizes, int n_in,
                              void* d_out, int out_size, void* d_ws, size_t ws_size,
                              hipStream_t stream) {
  const float* emb = (const float*)d_in[0];
  const float* Tw  = (const float*)d_in[1];
  const float* ugr = (const float*)d_in[2];
  const float* sps = (const float*)d_in[3];
  const float* ew  = (const float*)d_in[4];
  const int* esrc  = (const int*)d_in[5];
  const int* edst  = (const int*)d_in[6];
  const int* idx   = (const int*)d_in[7];
  float* out = (float*)d_out;

  const int N    = in_sizes[0] / 64;   // 49152
  const int TAGS = in_sizes[1] / 64;   // 1024
  const int NU   = in_sizes[2] / 64;   // 8192
  const int NI   = in_sizes[3] / TAGS; // 40960
  const int E    = in_sizes[4];        // 1572864
  const int B    = in_sizes[7] / 2;    // 131072
  const int NB   = N / 256;            // 192 scan blocks

  size_t rowsz = (size_t)N * 128 * sizeof(float);
  char* ws = (char*)d_ws;
  float* xt  = (float*)(ws);               // encoder layer-0 input
  float* b1  = (float*)(ws + rowsz);       // layer1 out; pb alias; h alias
  float* b2  = (float*)(ws + 2 * rowsz);   // layer2 out; stage alias
  float* gkg = (float*)(ws + 3 * rowsz);   // TAGS x 64
  size_t o = 3 * rowsz + (size_t)TAGS * 64 * sizeof(float);
  int* off  = (int*)(ws + o);  o += (size_t)(N + 1) * sizeof(int);
  int* pos  = (int*)(ws + o);  o += (size_t)N * sizeof(int);
  int* bsum = (int*)(ws + o);  o += (size_t)NB * sizeof(int);
  int* bof  = (int*)(ws + o);  o += (size_t)NB * sizeof(int);
  int* bcur = (int*)(ws + o);  o += (size_t)NBUK * sizeof(int);
  o = (o + 7) & ~(size_t)7;
  int2* rec = (int2*)(ws + o);             // E records (src, w)
  int2* stage = (int2*)b2;                 // E staged records (dead before gather2)
  float* pb = b1;                          // KSPLIT x NI x 64 partials
  float* h  = b1;                          // final embeddings, in-place over b1

  // CSR build
  hipMemsetAsync(pos, 0, (size_t)N * sizeof(int), stream);
  hipMemsetAsync(bcur, 0, (size_t)NBUK * sizeof(int), stream);
  k_hist<<<(E + 255) / 256, 256, 0, stream>>>(edst, pos, E);
  kb1<<<NB, 256, 0, stream>>>(pos, bsum);
  kb2<<<1, 256, 0, stream>>>(bsum, bof, off, NB, N, E);
  kb3<<<NB, 256, 0, stream>>>(pos, off, bof);
  k_passA<<<E / 2048, 256, 0, stream>>>(esrc, edst, ew, off, bcur, stage);
  k_passB<<<NBUK * 8, 256, 0, stream>>>(stage, off, pos, rec);

  // feature prep
  k_node_prep<<<(N + 3) / 4, 256, 0, stream>>>(emb, ugr, xt, N, NU);
  k_tag_prep<<<(TAGS + 3) / 4, 256, 0, stream>>>(Tw, gkg, TAGS);
  dim3 hgrid(NI / 64, KSPLIT);
  k_hyper<<<hgrid, 256, 0, stream>>>(sps, gkg, pb, NI);
  k_combine<<<(NI + 3) / 4, 256, 0, stream>>>(pb, xt, NI, NU);

  // 3 encoder layers (gather-side, no atomics); layer 3 fused with expmap
  k_gather<<<(N + 3) / 4, 256, 0, stream>>>(xt, b1, off, rec, N);
  k_gather<<<(N + 3) / 4, 256, 0, stream>>>(b1, b2, off, rec, N);
  k_gather_exp<<<(N + 3) / 4, 256, 0, stream>>>(b2, b1, b2, off, rec, h, N);

  k_score<<<(B / 4 + 3) / 4, 256, 0, stream>>>(h, idx, out, B);
}